// Round 4
// baseline (888.861 us; speedup 1.0000x reference)
//
#include <hip/hip_runtime.h>
#include <cstddef>

// EGNN layer. Round 4: transposed MFMA orientation (channels = M, edges/nodes = N).
// N=50000 nodes, M=800000 edges, H=64, E=16, IN_E=145.
//
// Key trick: A-frag and B-frag have the same lane mapping (m/n = lane&15,
// k = (lane>>4)*8+j), so swapping MFMA operand order transposes the GEMM.
// Weights become A-frags (same register data as round 3's B-frags); per-edge /
// per-node data becomes B-frags loaded DIRECTLY from global (32B/lane).
// C-layout then gives each lane 4 consecutive channels of one edge/node:
//   - hA/hB gathers are float4 loads (was 32 scalar loads -> 8 vector loads)
//   - outputs store as float4; msg atomics hit 4 consecutive addresses
//   - coord reduction needs only shfl_xor(16), shfl_xor(32)
// node_pre and node_kernel also converted to MFMA with the same structure.
//
// MFMA fragment layouts (gfx950, 16x16x32 bf16, verified learn_hip m89/m91):
//   A: lane holds A[m=lane&15][k=(lane>>4)*8 + j], j=0..7
//   B: lane holds B[k=(lane>>4)*8 + j][n=lane&15]
//   C/D: lane reg r holds D[row=(lane>>4)*4+r][col=lane&15]

#define N_NODES 50000
#define M_EDGES 800000

typedef __attribute__((ext_vector_type(8))) short bf16x8;
typedef __attribute__((ext_vector_type(4))) short bf16x4;
typedef __attribute__((ext_vector_type(4))) float f32x4;

__device__ __forceinline__ float silu_f(float v) {
    return v / (1.0f + __expf(-v));
}

__device__ __forceinline__ short f2bf(float f) {   // RNE float->bf16
    union { float f; unsigned u; } v; v.f = f;
    unsigned r = v.u + 0x7fffu + ((v.u >> 16) & 1u);
    return (short)(r >> 16);
}

#define LDS_FENCE() __asm__ volatile("" ::: "memory")

// ---------------------------------------------------------------- K1: hA/hB
// hA' = Wa^T @ h', hB' = Wb^T @ h'. A = weight frags (regs), B = h rows (global).
__global__ __launch_bounds__(256, 3) void node_pre_kernel(
    const float* __restrict__ h, const float* __restrict__ w1e,
    float* __restrict__ hA, float* __restrict__ hB)
{
    const int tid  = threadIdx.x;
    const int lane = tid & 63;
    const int wv   = __builtin_amdgcn_readfirstlane(tid >> 6);
    const int l15  = lane & 15;
    const int l4   = lane >> 4;

    bf16x8 wa[4][2], wb[4][2];
    #pragma unroll
    for (int t = 0; t < 4; ++t)
        #pragma unroll
        for (int s = 0; s < 2; ++s) {
            bf16x8 fa, fb;
            #pragma unroll
            for (int j = 0; j < 8; ++j) {
                const int k = s * 32 + l4 * 8 + j;
                fa[j] = f2bf(w1e[(size_t)(1 + k) * 64 + t * 16 + l15]);
                fb[j] = f2bf(w1e[(size_t)(65 + k) * 64 + t * 16 + l15]);
            }
            wa[t][s] = fa; wb[t][s] = fb;
        }

    const int n16  = blockIdx.x * 64 + wv * 16 + l15;
    const int nc   = (n16 < N_NODES) ? n16 : 0;
    const bool valid = (n16 < N_NODES);

    const float* hp = h + (size_t)nc * 64;
    bf16x8 bh[2];
    #pragma unroll
    for (int s = 0; s < 2; ++s) {
        const f32x4 f0 = *(const f32x4*)(hp + s * 32 + l4 * 8);
        const f32x4 f1 = *(const f32x4*)(hp + s * 32 + l4 * 8 + 4);
        bf16x8 bv;
        #pragma unroll
        for (int j = 0; j < 4; ++j) { bv[j] = f2bf(f0[j]); bv[4 + j] = f2bf(f1[j]); }
        bh[s] = bv;
    }

    const f32x4 zf = {0.f, 0.f, 0.f, 0.f};
    #pragma unroll
    for (int t = 0; t < 4; ++t) {
        f32x4 aA = __builtin_amdgcn_mfma_f32_16x16x32_bf16(wa[t][0], bh[0], zf, 0, 0, 0);
        aA = __builtin_amdgcn_mfma_f32_16x16x32_bf16(wa[t][1], bh[1], aA, 0, 0, 0);
        f32x4 aB = __builtin_amdgcn_mfma_f32_16x16x32_bf16(wb[t][0], bh[0], zf, 0, 0, 0);
        aB = __builtin_amdgcn_mfma_f32_16x16x32_bf16(wb[t][1], bh[1], aB, 0, 0, 0);
        if (valid) {
            *(f32x4*)&hA[(size_t)n16 * 64 + t * 16 + l4 * 4] = aA;
            *(f32x4*)&hB[(size_t)n16 * 64 + t * 16 + l4 * 4] = aB;
        }
    }
}

// ---------------------------------------------------------------- K2: edges
__global__ __launch_bounds__(256, 3) void edge_kernel(
    const float* __restrict__ x, const float* __restrict__ edge_fea,
    const float* __restrict__ w1e, const float* __restrict__ b1e,
    const float* __restrict__ w2e, const float* __restrict__ b2e,
    const float* __restrict__ wc1, const float* __restrict__ bc1,
    const float* __restrict__ wc2, const float* __restrict__ bc2,
    const int* __restrict__ row, const int* __restrict__ col,
    const float* __restrict__ hA, const float* __restrict__ hB,
    float* __restrict__ tot_msg, float* __restrict__ totf4)
{
    __shared__ __align__(16) short w2t_s[64 * 72];   // w2e  [n][k] bf16
    __shared__ __align__(16) short wc1t_s[64 * 72];  // wc1  [n][k] bf16
    __shared__ __align__(16) short u_s[4][16 * 72];  // per-wave [edge][ch] tile
    __shared__ f32x4 rs_s[4][16];                    // (dx,dy,dz,sq)
    __shared__ int2  ri_s[4][16];                    // (row,col)
    __shared__ f32x4 cst_s[5][16];                   // b1,w1r0,b2,bc1,wc2 by [t*4+l4]

    const int tid  = threadIdx.x;
    const int lane = tid & 63;
    const int wv   = __builtin_amdgcn_readfirstlane(tid >> 6);
    const int l15  = lane & 15;
    const int l4   = lane >> 4;

    // ---- stage transposed bf16 weights + f32x4 constants (once per block)
    for (int i = tid; i < 4096; i += 256) {
        const int k = i >> 6, n = i & 63;
        w2t_s[n * 72 + k]  = f2bf(w2e[i]);
        wc1t_s[n * 72 + k] = f2bf(wc1[i]);
    }
    if (tid < 16)       cst_s[0][tid]      = *(const f32x4*)(b1e + tid * 4);
    else if (tid < 32)  cst_s[1][tid - 16] = *(const f32x4*)(w1e + (tid - 16) * 4);
    else if (tid < 48)  cst_s[2][tid - 32] = *(const f32x4*)(b2e + (tid - 32) * 4);
    else if (tid < 64)  cst_s[3][tid - 48] = *(const f32x4*)(bc1 + (tid - 48) * 4);
    else if (tid < 80)  cst_s[4][tid - 64] = *(const f32x4*)(wc2 + (tid - 64) * 4);
    __syncthreads();

    // ---- weight A-frags in registers (same lane data as round-3 B-frags)
    bf16x8 bw2f[4][2], bwc1f[4][2], bw1cf[4];
    #pragma unroll
    for (int t = 0; t < 4; ++t) {
        #pragma unroll
        for (int s = 0; s < 2; ++s) {
            bw2f[t][s]  = *(const bf16x8*)&w2t_s[(t * 16 + l15) * 72 + s * 32 + l4 * 8];
            bwc1f[t][s] = *(const bf16x8*)&wc1t_s[(t * 16 + l15) * 72 + s * 32 + l4 * 8];
        }
        bf16x8 wf;
        #pragma unroll
        for (int b = 0; b < 8; ++b) {
            const int k = l4 * 8 + b;
            wf[b] = (k < 16) ? f2bf(w1e[(size_t)(129 + k) * 64 + t * 16 + l15]) : (short)0;
        }
        bw1cf[t] = wf;
    }
    const float bc2v = bc2[0];
    short* const us = &u_s[wv][0];
    const f32x4 zf = {0.f, 0.f, 0.f, 0.f};

    for (int g = blockIdx.x; g < M_EDGES / 64; g += gridDim.x) {
        const int ebase = g * 64 + wv * 16;

        // ---- stage indices, rij, sq (one edge per lane, 16 lanes)
        if (lane < 16) {
            const int e = ebase + lane;
            const int r = row[e], c = col[e];
            ri_s[wv][lane] = make_int2(r, c);
            const float dx = x[r * 3 + 0] - x[c * 3 + 0];
            const float dy = x[r * 3 + 1] - x[c * 3 + 1];
            const float dz = x[r * 3 + 2] - x[c * 3 + 2];
            f32x4 rv; rv[0] = dx; rv[1] = dy; rv[2] = dz; rv[3] = dx * dx + dy * dy + dz * dz;
            rs_s[wv][lane] = rv;
        }

        // ---- fea B-frag: direct global read (k>=16 lanes carry zeros)
        const int e16 = ebase + l15;
        bf16x8 bfea;
        {
            const float* fp = edge_fea + (size_t)e16 * 16 + (l4 & 1) * 8;
            const f32x4 f0 = *(const f32x4*)fp;
            const f32x4 f1 = *(const f32x4*)(fp + 4);
            bf16x8 tv;
            #pragma unroll
            for (int j = 0; j < 4; ++j) { tv[j] = f2bf(f0[j]); tv[4 + j] = f2bf(f1[j]); }
            const bf16x8 zv = {0, 0, 0, 0, 0, 0, 0, 0};
            bfea = (l4 < 2) ? tv : zv;
        }
        LDS_FENCE();

        // ---- layer1 partial: W1c^T @ fea'
        f32x4 acc1[4];
        #pragma unroll
        for (int t = 0; t < 4; ++t)
            acc1[t] = __builtin_amdgcn_mfma_f32_16x16x32_bf16(bw1cf[t], bfea, zf, 0, 0, 0);

        const int2 rc = ri_s[wv][l15];
        const int rIdx = rc.x, cIdx = rc.y;
        const f32x4 rsv = rs_s[wv][l15];
        const float sq = rsv[3];

        // ---- finish layer1: float4 gathers of hA/hB, silu, bf16x4 -> LDS
        #pragma unroll
        for (int t = 0; t < 4; ++t) {
            const f32x4 ha  = *(const f32x4*)&hA[(size_t)rIdx * 64 + t * 16 + l4 * 4];
            const f32x4 hb  = *(const f32x4*)&hB[(size_t)cIdx * 64 + t * 16 + l4 * 4];
            const f32x4 b1v = cst_s[0][t * 4 + l4];
            const f32x4 w0v = cst_s[1][t * 4 + l4];
            bf16x4 uu;
            #pragma unroll
            for (int r = 0; r < 4; ++r) {
                const float pre = acc1[t][r] + ha[r] + hb[r] + sq * w0v[r] + b1v[r];
                uu[r] = f2bf(silu_f(pre));
            }
            *(bf16x4*)&us[l15 * 72 + t * 16 + l4 * 4] = uu;
        }
        LDS_FENCE();

        // ---- layer2: msg' = silu(W2^T @ u1' + b2)
        f32x4 acc2[4];
        {
            const bf16x8 a0 = *(const bf16x8*)&us[l15 * 72 + l4 * 8];
            const bf16x8 a1 = *(const bf16x8*)&us[l15 * 72 + 32 + l4 * 8];
            #pragma unroll
            for (int t = 0; t < 4; ++t) {
                acc2[t] = __builtin_amdgcn_mfma_f32_16x16x32_bf16(bw2f[t][0], a0, zf, 0, 0, 0);
                acc2[t] = __builtin_amdgcn_mfma_f32_16x16x32_bf16(bw2f[t][1], a1, acc2[t], 0, 0, 0);
            }
        }
        LDS_FENCE();
        #pragma unroll
        for (int t = 0; t < 4; ++t) {
            const f32x4 b2v = cst_s[2][t * 4 + l4];
            float* const mb = &tot_msg[(size_t)rIdx * 64 + t * 16 + l4 * 4];
            bf16x4 mm;
            #pragma unroll
            for (int r = 0; r < 4; ++r) {
                const float m = silu_f(acc2[t][r] + b2v[r]);
                atomicAdd(mb + r, m);
                mm[r] = f2bf(m);
            }
            *(bf16x4*)&us[l15 * 72 + t * 16 + l4 * 4] = mm;
        }
        LDS_FENCE();

        // ---- layer3 + coord head
        f32x4 acc3[4];
        {
            const bf16x8 a0 = *(const bf16x8*)&us[l15 * 72 + l4 * 8];
            const bf16x8 a1 = *(const bf16x8*)&us[l15 * 72 + 32 + l4 * 8];
            #pragma unroll
            for (int t = 0; t < 4; ++t) {
                acc3[t] = __builtin_amdgcn_mfma_f32_16x16x32_bf16(bwc1f[t][0], a0, zf, 0, 0, 0);
                acc3[t] = __builtin_amdgcn_mfma_f32_16x16x32_bf16(bwc1f[t][1], a1, acc3[t], 0, 0, 0);
            }
        }
        float p = 0.f;
        #pragma unroll
        for (int t = 0; t < 4; ++t) {
            const f32x4 bcv = cst_s[3][t * 4 + l4];
            const f32x4 wcv = cst_s[4][t * 4 + l4];
            #pragma unroll
            for (int r = 0; r < 4; ++r)
                p += silu_f(acc3[t][r] + bcv[r]) * wcv[r];
        }
        p += __shfl_xor(p, 16);
        p += __shfl_xor(p, 32);
        const float coord = p + bc2v;

        // ---- totf4 atomic: lane -> (edge=l15, comp=l4)
        const float comp = (l4 == 0) ? rsv[0] : (l4 == 1) ? rsv[1] : (l4 == 2) ? rsv[2] : 0.f;
        const float val  = (l4 == 3) ? 1.0f : comp * coord;
        atomicAdd(&totf4[(size_t)rIdx * 4 + l4], val);
    }
}

// ---------------------------------------------------------------- K3: nodes
__global__ __launch_bounds__(256, 2) void node_kernel(
    const float* __restrict__ x, const float* __restrict__ h,
    const float* __restrict__ wn1, const float* __restrict__ bn1,
    const float* __restrict__ wn2, const float* __restrict__ bn2,
    const float* __restrict__ tot_msg, const float* __restrict__ totf4,
    float* __restrict__ out)
{
    __shared__ __align__(16) short g_s[4][16 * 72];

    const int tid  = threadIdx.x;
    const int lane = tid & 63;
    const int wv   = __builtin_amdgcn_readfirstlane(tid >> 6);
    const int l15  = lane & 15;
    const int l4   = lane >> 4;

    // weight A-frags: wn1^T (K=128 -> 4 frags/tile), wn2^T (2 frags/tile)
    bf16x8 awn1[4][4], awn2[4][2];
    f32x4 bn1r4[4], bn2r4[4];
    #pragma unroll
    for (int t = 0; t < 4; ++t) {
        #pragma unroll
        for (int s = 0; s < 4; ++s) {
            bf16x8 fv;
            #pragma unroll
            for (int j = 0; j < 8; ++j)
                fv[j] = f2bf(wn1[(size_t)(s * 32 + l4 * 8 + j) * 64 + t * 16 + l15]);
            awn1[t][s] = fv;
        }
        #pragma unroll
        for (int s = 0; s < 2; ++s) {
            bf16x8 fv;
            #pragma unroll
            for (int j = 0; j < 8; ++j)
                fv[j] = f2bf(wn2[(size_t)(s * 32 + l4 * 8 + j) * 64 + t * 16 + l15]);
            awn2[t][s] = fv;
        }
        bn1r4[t] = *(const f32x4*)&bn1[t * 16 + l4 * 4];
        bn2r4[t] = *(const f32x4*)&bn2[t * 16 + l4 * 4];
    }

    const int n16  = blockIdx.x * 64 + wv * 16 + l15;
    const int nc   = (n16 < N_NODES) ? n16 : 0;
    const bool valid = (n16 < N_NODES);

    // B-frags: [h | tot_msg] rows, direct global loads
    bf16x8 b[4];
    #pragma unroll
    for (int s = 0; s < 4; ++s) {
        const float* src = (s < 2) ? (h + (size_t)nc * 64 + s * 32 + l4 * 8)
                                   : (tot_msg + (size_t)nc * 64 + (s - 2) * 32 + l4 * 8);
        const f32x4 f0 = *(const f32x4*)src;
        const f32x4 f1 = *(const f32x4*)(src + 4);
        bf16x8 bv;
        #pragma unroll
        for (int j = 0; j < 4; ++j) { bv[j] = f2bf(f0[j]); bv[4 + j] = f2bf(f1[j]); }
        b[s] = bv;
    }

    const f32x4 zf = {0.f, 0.f, 0.f, 0.f};
    #pragma unroll
    for (int t = 0; t < 4; ++t) {
        f32x4 acc = __builtin_amdgcn_mfma_f32_16x16x32_bf16(awn1[t][0], b[0], zf, 0, 0, 0);
        acc = __builtin_amdgcn_mfma_f32_16x16x32_bf16(awn1[t][1], b[1], acc, 0, 0, 0);
        acc = __builtin_amdgcn_mfma_f32_16x16x32_bf16(awn1[t][2], b[2], acc, 0, 0, 0);
        acc = __builtin_amdgcn_mfma_f32_16x16x32_bf16(awn1[t][3], b[3], acc, 0, 0, 0);
        bf16x4 gg;
        #pragma unroll
        for (int r = 0; r < 4; ++r)
            gg[r] = f2bf(silu_f(acc[r] + bn1r4[t][r]));
        *(bf16x4*)&g_s[wv][l15 * 72 + t * 16 + l4 * 4] = gg;
    }
    LDS_FENCE();

    {
        const bf16x8 g0 = *(const bf16x8*)&g_s[wv][l15 * 72 + l4 * 8];
        const bf16x8 g1 = *(const bf16x8*)&g_s[wv][l15 * 72 + 32 + l4 * 8];
        float* const out_h = out + (size_t)N_NODES * 3;
        #pragma unroll
        for (int t = 0; t < 4; ++t) {
            f32x4 acc = __builtin_amdgcn_mfma_f32_16x16x32_bf16(awn2[t][0], g0, zf, 0, 0, 0);
            acc = __builtin_amdgcn_mfma_f32_16x16x32_bf16(awn2[t][1], g1, acc, 0, 0, 0);
            if (valid) {
                f32x4 o;
                #pragma unroll
                for (int r = 0; r < 4; ++r) o[r] = acc[r] + bn2r4[t][r];
                *(f32x4*)&out_h[(size_t)n16 * 64 + t * 16 + l4 * 4] = o;
            }
        }
    }

    // x_new = x + clamp(tot_f / max(deg,1), +-100): 48 lanes -> 16 nodes x 3
    if (lane < 48) {
        const int nn = lane / 3;
        const int ci = lane % 3;
        const int n  = blockIdx.x * 64 + wv * 16 + nn;
        if (n < N_NODES) {
            const float tot = totf4[n * 4 + ci];
            const float deg = totf4[n * 4 + 3];
            float v = tot / fmaxf(deg, 1.0f);
            v = fminf(fmaxf(v, -100.0f), 100.0f);
            out[n * 3 + ci] = x[n * 3 + ci] + v;
        }
    }
}

// ---------------------------------------------------------------- launcher
extern "C" void kernel_launch(void* const* d_in, const int* in_sizes, int n_in,
                              void* d_out, int out_size, void* d_ws, size_t ws_size,
                              hipStream_t stream) {
    const float* x        = (const float*)d_in[0];
    const float* h        = (const float*)d_in[1];
    const float* edge_fea = (const float*)d_in[2];
    const float* w1e      = (const float*)d_in[3];
    const float* b1e      = (const float*)d_in[4];
    const float* w2e      = (const float*)d_in[5];
    const float* b2e      = (const float*)d_in[6];
    const float* wc1      = (const float*)d_in[7];
    const float* bc1      = (const float*)d_in[8];
    const float* wc2      = (const float*)d_in[9];
    const float* bc2      = (const float*)d_in[10];
    const float* wn1      = (const float*)d_in[11];
    const float* bn1      = (const float*)d_in[12];
    const float* wn2      = (const float*)d_in[13];
    const float* bn2      = (const float*)d_in[14];
    const int*   row      = (const int*)d_in[15];
    const int*   col      = (const int*)d_in[16];
    float* out = (float*)d_out;

    // ws layout (floats): hA[N*64] | hB[N*64] | tot_msg[N*64] | totf4[N*4]
    float* ws      = (float*)d_ws;
    float* hA      = ws;
    float* hB      = ws + (size_t)N_NODES * 64;
    float* tot_msg = ws + (size_t)2 * N_NODES * 64;
    float* totf4   = ws + (size_t)3 * N_NODES * 64;

    hipMemsetAsync(tot_msg, 0, (size_t)(N_NODES * 64 + N_NODES * 4) * sizeof(float), stream);

    const int node_grid = (N_NODES + 63) / 64;   // 782
    node_pre_kernel<<<node_grid, 256, 0, stream>>>(h, w1e, hA, hB);
    edge_kernel<<<2048, 256, 0, stream>>>(x, edge_fea, w1e, b1e, w2e, b2e,
                                          wc1, bc1, wc2, bc2, row, col,
                                          hA, hB, tot_msg, totf4);
    node_kernel<<<node_grid, 256, 0, stream>>>(x, h, wn1, bn1, wn2, bn2,
                                               tot_msg, totf4, out);
}

// Round 5
// 404.785 us; speedup vs baseline: 2.1959x; 2.1959x over previous
//
#include <hip/hip_runtime.h>
#include <cstddef>

// EGNN layer. Round 5: round-4 transposed-MFMA compute + round-3 coalesced
// atomic pattern (the round-4 regression was 4x atomic write amplification:
// 16B useful per 64B line-transaction; WRITE_SIZE 225->825 MB, dur 249->750).
// tot_msg atomics now re-read the LDS msg tile in [4 rows x 16 consecutive
// channels] per instruction -> full-line coalescing.
// Node kernels: grid-stride loops amortize weight-fragment prologues.
//
// MFMA fragment layouts (gfx950, 16x16x32 bf16, verified learn_hip m89/m91):
//   A: lane holds A[m=lane&15][k=(lane>>4)*8 + j], j=0..7
//   B: lane holds B[k=(lane>>4)*8 + j][n=lane&15]
//   C/D: lane reg r holds D[row=(lane>>4)*4+r][col=lane&15]

#define N_NODES 50000
#define M_EDGES 800000

typedef __attribute__((ext_vector_type(8))) short bf16x8;
typedef __attribute__((ext_vector_type(4))) short bf16x4;
typedef __attribute__((ext_vector_type(4))) float f32x4;

__device__ __forceinline__ float silu_f(float v) {
    return v / (1.0f + __expf(-v));
}

__device__ __forceinline__ short f2bf(float f) {   // RNE float->bf16
    union { float f; unsigned u; } v; v.f = f;
    unsigned r = v.u + 0x7fffu + ((v.u >> 16) & 1u);
    return (short)(r >> 16);
}

__device__ __forceinline__ float bf2f(short s) {
    union { unsigned u; float f; } v;
    v.u = ((unsigned)(unsigned short)s) << 16;
    return v.f;
}

#define LDS_FENCE() __asm__ volatile("" ::: "memory")

// ---------------------------------------------------------------- K1: hA/hB
__global__ __launch_bounds__(256, 3) void node_pre_kernel(
    const float* __restrict__ h, const float* __restrict__ w1e,
    float* __restrict__ hA, float* __restrict__ hB)
{
    const int tid  = threadIdx.x;
    const int lane = tid & 63;
    const int wv   = __builtin_amdgcn_readfirstlane(tid >> 6);
    const int l15  = lane & 15;
    const int l4   = lane >> 4;

    bf16x8 wa[4][2], wb[4][2];
    #pragma unroll
    for (int t = 0; t < 4; ++t)
        #pragma unroll
        for (int s = 0; s < 2; ++s) {
            bf16x8 fa, fb;
            #pragma unroll
            for (int j = 0; j < 8; ++j) {
                const int k = s * 32 + l4 * 8 + j;
                fa[j] = f2bf(w1e[(size_t)(1 + k) * 64 + t * 16 + l15]);
                fb[j] = f2bf(w1e[(size_t)(65 + k) * 64 + t * 16 + l15]);
            }
            wa[t][s] = fa; wb[t][s] = fb;
        }

    const f32x4 zf = {0.f, 0.f, 0.f, 0.f};
    const int n_groups = (N_NODES + 63) / 64;

    for (int g = blockIdx.x; g < n_groups; g += gridDim.x) {
        const int n16  = g * 64 + wv * 16 + l15;
        const int nc   = (n16 < N_NODES) ? n16 : 0;
        const bool valid = (n16 < N_NODES);

        const float* hp = h + (size_t)nc * 64;
        bf16x8 bh[2];
        #pragma unroll
        for (int s = 0; s < 2; ++s) {
            const f32x4 f0 = *(const f32x4*)(hp + s * 32 + l4 * 8);
            const f32x4 f1 = *(const f32x4*)(hp + s * 32 + l4 * 8 + 4);
            bf16x8 bv;
            #pragma unroll
            for (int j = 0; j < 4; ++j) { bv[j] = f2bf(f0[j]); bv[4 + j] = f2bf(f1[j]); }
            bh[s] = bv;
        }

        #pragma unroll
        for (int t = 0; t < 4; ++t) {
            f32x4 aA = __builtin_amdgcn_mfma_f32_16x16x32_bf16(wa[t][0], bh[0], zf, 0, 0, 0);
            aA = __builtin_amdgcn_mfma_f32_16x16x32_bf16(wa[t][1], bh[1], aA, 0, 0, 0);
            f32x4 aB = __builtin_amdgcn_mfma_f32_16x16x32_bf16(wb[t][0], bh[0], zf, 0, 0, 0);
            aB = __builtin_amdgcn_mfma_f32_16x16x32_bf16(wb[t][1], bh[1], aB, 0, 0, 0);
            if (valid) {
                *(f32x4*)&hA[(size_t)n16 * 64 + t * 16 + l4 * 4] = aA;
                *(f32x4*)&hB[(size_t)n16 * 64 + t * 16 + l4 * 4] = aB;
            }
        }
    }
}

// ---------------------------------------------------------------- K2: edges
__global__ __launch_bounds__(256, 3) void edge_kernel(
    const float* __restrict__ x, const float* __restrict__ edge_fea,
    const float* __restrict__ w1e, const float* __restrict__ b1e,
    const float* __restrict__ w2e, const float* __restrict__ b2e,
    const float* __restrict__ wc1, const float* __restrict__ bc1,
    const float* __restrict__ wc2, const float* __restrict__ bc2,
    const int* __restrict__ row, const int* __restrict__ col,
    const float* __restrict__ hA, const float* __restrict__ hB,
    float* __restrict__ tot_msg, float* __restrict__ totf4)
{
    __shared__ __align__(16) short w2t_s[64 * 72];   // w2e  [n][k] bf16
    __shared__ __align__(16) short wc1t_s[64 * 72];  // wc1  [n][k] bf16
    __shared__ __align__(16) short u_s[4][16 * 72];  // per-wave [edge][ch] tile
    __shared__ f32x4 rs_s[4][16];                    // (dx,dy,dz,sq)
    __shared__ int2  ri_s[4][16];                    // (row,col)
    __shared__ f32x4 cst_s[5][16];                   // b1,w1r0,b2,bc1,wc2 by [t*4+l4]

    const int tid  = threadIdx.x;
    const int lane = tid & 63;
    const int wv   = __builtin_amdgcn_readfirstlane(tid >> 6);
    const int l15  = lane & 15;
    const int l4   = lane >> 4;

    // ---- stage transposed bf16 weights + f32x4 constants (once per block)
    for (int i = tid; i < 4096; i += 256) {
        const int k = i >> 6, n = i & 63;
        w2t_s[n * 72 + k]  = f2bf(w2e[i]);
        wc1t_s[n * 72 + k] = f2bf(wc1[i]);
    }
    if (tid < 16)       cst_s[0][tid]      = *(const f32x4*)(b1e + tid * 4);
    else if (tid < 32)  cst_s[1][tid - 16] = *(const f32x4*)(w1e + (tid - 16) * 4);
    else if (tid < 48)  cst_s[2][tid - 32] = *(const f32x4*)(b2e + (tid - 32) * 4);
    else if (tid < 64)  cst_s[3][tid - 48] = *(const f32x4*)(bc1 + (tid - 48) * 4);
    else if (tid < 80)  cst_s[4][tid - 64] = *(const f32x4*)(wc2 + (tid - 64) * 4);
    __syncthreads();

    // ---- weight A-frags in registers
    bf16x8 bw2f[4][2], bwc1f[4][2], bw1cf[4];
    #pragma unroll
    for (int t = 0; t < 4; ++t) {
        #pragma unroll
        for (int s = 0; s < 2; ++s) {
            bw2f[t][s]  = *(const bf16x8*)&w2t_s[(t * 16 + l15) * 72 + s * 32 + l4 * 8];
            bwc1f[t][s] = *(const bf16x8*)&wc1t_s[(t * 16 + l15) * 72 + s * 32 + l4 * 8];
        }
        bf16x8 wf;
        #pragma unroll
        for (int b = 0; b < 8; ++b) {
            const int k = l4 * 8 + b;
            wf[b] = (k < 16) ? f2bf(w1e[(size_t)(129 + k) * 64 + t * 16 + l15]) : (short)0;
        }
        bw1cf[t] = wf;
    }
    const float bc2v = bc2[0];
    short* const us = &u_s[wv][0];
    const f32x4 zf = {0.f, 0.f, 0.f, 0.f};

    for (int g = blockIdx.x; g < M_EDGES / 64; g += gridDim.x) {
        const int ebase = g * 64 + wv * 16;

        // ---- stage indices, rij, sq (one edge per lane, 16 lanes)
        if (lane < 16) {
            const int e = ebase + lane;
            const int r = row[e], c = col[e];
            ri_s[wv][lane] = make_int2(r, c);
            const float dx = x[r * 3 + 0] - x[c * 3 + 0];
            const float dy = x[r * 3 + 1] - x[c * 3 + 1];
            const float dz = x[r * 3 + 2] - x[c * 3 + 2];
            f32x4 rv; rv[0] = dx; rv[1] = dy; rv[2] = dz; rv[3] = dx * dx + dy * dy + dz * dz;
            rs_s[wv][lane] = rv;
        }

        // ---- fea B-frag: direct global read (k>=16 lanes carry zeros)
        const int e16 = ebase + l15;
        bf16x8 bfea;
        {
            const float* fp = edge_fea + (size_t)e16 * 16 + (l4 & 1) * 8;
            const f32x4 f0 = *(const f32x4*)fp;
            const f32x4 f1 = *(const f32x4*)(fp + 4);
            bf16x8 tv;
            #pragma unroll
            for (int j = 0; j < 4; ++j) { tv[j] = f2bf(f0[j]); tv[4 + j] = f2bf(f1[j]); }
            const bf16x8 zv = {0, 0, 0, 0, 0, 0, 0, 0};
            bfea = (l4 < 2) ? tv : zv;
        }
        LDS_FENCE();

        // ---- layer1 partial: W1c^T @ fea'
        f32x4 acc1[4];
        #pragma unroll
        for (int t = 0; t < 4; ++t)
            acc1[t] = __builtin_amdgcn_mfma_f32_16x16x32_bf16(bw1cf[t], bfea, zf, 0, 0, 0);

        const int2 rc = ri_s[wv][l15];
        const int rIdx = rc.x, cIdx = rc.y;
        const f32x4 rsv = rs_s[wv][l15];
        const float sq = rsv[3];

        // ---- finish layer1: float4 gathers of hA/hB, silu, bf16x4 -> LDS
        #pragma unroll
        for (int t = 0; t < 4; ++t) {
            const f32x4 ha  = *(const f32x4*)&hA[(size_t)rIdx * 64 + t * 16 + l4 * 4];
            const f32x4 hb  = *(const f32x4*)&hB[(size_t)cIdx * 64 + t * 16 + l4 * 4];
            const f32x4 b1v = cst_s[0][t * 4 + l4];
            const f32x4 w0v = cst_s[1][t * 4 + l4];
            bf16x4 uu;
            #pragma unroll
            for (int r = 0; r < 4; ++r) {
                const float pre = acc1[t][r] + ha[r] + hb[r] + sq * w0v[r] + b1v[r];
                uu[r] = f2bf(silu_f(pre));
            }
            *(bf16x4*)&us[l15 * 72 + t * 16 + l4 * 4] = uu;
        }
        LDS_FENCE();

        // ---- layer2: msg' = silu(W2^T @ u1' + b2), store bf16 tile
        f32x4 acc2[4];
        {
            const bf16x8 a0 = *(const bf16x8*)&us[l15 * 72 + l4 * 8];
            const bf16x8 a1 = *(const bf16x8*)&us[l15 * 72 + 32 + l4 * 8];
            #pragma unroll
            for (int t = 0; t < 4; ++t) {
                acc2[t] = __builtin_amdgcn_mfma_f32_16x16x32_bf16(bw2f[t][0], a0, zf, 0, 0, 0);
                acc2[t] = __builtin_amdgcn_mfma_f32_16x16x32_bf16(bw2f[t][1], a1, acc2[t], 0, 0, 0);
            }
        }
        LDS_FENCE();
        #pragma unroll
        for (int t = 0; t < 4; ++t) {
            const f32x4 b2v = cst_s[2][t * 4 + l4];
            bf16x4 mm;
            #pragma unroll
            for (int r = 0; r < 4; ++r)
                mm[r] = f2bf(silu_f(acc2[t][r] + b2v[r]));
            *(bf16x4*)&us[l15 * 72 + t * 16 + l4 * 4] = mm;
        }
        LDS_FENCE();

        // ---- layer3 + coord head (MFMAs issued before the atomic block)
        f32x4 acc3[4];
        {
            const bf16x8 a0 = *(const bf16x8*)&us[l15 * 72 + l4 * 8];
            const bf16x8 a1 = *(const bf16x8*)&us[l15 * 72 + 32 + l4 * 8];
            #pragma unroll
            for (int t = 0; t < 4; ++t) {
                acc3[t] = __builtin_amdgcn_mfma_f32_16x16x32_bf16(bwc1f[t][0], a0, zf, 0, 0, 0);
                acc3[t] = __builtin_amdgcn_mfma_f32_16x16x32_bf16(bwc1f[t][1], a1, acc3[t], 0, 0, 0);
            }
        }

        // ---- tot_msg atomics, COALESCED pattern: per instruction the wave
        // covers 4 rows x 16 consecutive channels (full 64B lines).
        // lane -> edge er = l4*4+r (r unrolled), channel t*16+l15.
        #pragma unroll
        for (int r = 0; r < 4; ++r) {
            const int er   = l4 * 4 + r;
            const int rowr = ri_s[wv][er].x;
            float* const mb = &tot_msg[(size_t)rowr * 64 + l15];
            #pragma unroll
            for (int t = 0; t < 4; ++t) {
                const float mv = bf2f(us[er * 72 + t * 16 + l15]);
                atomicAdd(mb + t * 16, mv);
            }
        }

        // ---- coord head tail
        float p = 0.f;
        #pragma unroll
        for (int t = 0; t < 4; ++t) {
            const f32x4 bcv = cst_s[3][t * 4 + l4];
            const f32x4 wcv = cst_s[4][t * 4 + l4];
            #pragma unroll
            for (int r = 0; r < 4; ++r)
                p += silu_f(acc3[t][r] + bcv[r]) * wcv[r];
        }
        p += __shfl_xor(p, 16);
        p += __shfl_xor(p, 32);
        const float coord = p + bc2v;

        // ---- totf4 atomic: lane -> (edge=l15, comp=l4)
        const float comp = (l4 == 0) ? rsv[0] : (l4 == 1) ? rsv[1] : (l4 == 2) ? rsv[2] : 0.f;
        const float val  = (l4 == 3) ? 1.0f : comp * coord;
        atomicAdd(&totf4[(size_t)rIdx * 4 + l4], val);
    }
}

// ---------------------------------------------------------------- K3: nodes
__global__ __launch_bounds__(256, 2) void node_kernel(
    const float* __restrict__ x, const float* __restrict__ h,
    const float* __restrict__ wn1, const float* __restrict__ bn1,
    const float* __restrict__ wn2, const float* __restrict__ bn2,
    const float* __restrict__ tot_msg, const float* __restrict__ totf4,
    float* __restrict__ out)
{
    __shared__ __align__(16) short g_s[4][16 * 72];

    const int tid  = threadIdx.x;
    const int lane = tid & 63;
    const int wv   = __builtin_amdgcn_readfirstlane(tid >> 6);
    const int l15  = lane & 15;
    const int l4   = lane >> 4;

    // weight A-frags: wn1^T (K=128 -> 4 frags/tile), wn2^T (2 frags/tile)
    bf16x8 awn1[4][4], awn2[4][2];
    f32x4 bn1r4[4], bn2r4[4];
    #pragma unroll
    for (int t = 0; t < 4; ++t) {
        #pragma unroll
        for (int s = 0; s < 4; ++s) {
            bf16x8 fv;
            #pragma unroll
            for (int j = 0; j < 8; ++j)
                fv[j] = f2bf(wn1[(size_t)(s * 32 + l4 * 8 + j) * 64 + t * 16 + l15]);
            awn1[t][s] = fv;
        }
        #pragma unroll
        for (int s = 0; s < 2; ++s) {
            bf16x8 fv;
            #pragma unroll
            for (int j = 0; j < 8; ++j)
                fv[j] = f2bf(wn2[(size_t)(s * 32 + l4 * 8 + j) * 64 + t * 16 + l15]);
            awn2[t][s] = fv;
        }
        bn1r4[t] = *(const f32x4*)&bn1[t * 16 + l4 * 4];
        bn2r4[t] = *(const f32x4*)&bn2[t * 16 + l4 * 4];
    }

    const f32x4 zf = {0.f, 0.f, 0.f, 0.f};
    const int n_groups = (N_NODES + 63) / 64;
    float* const out_h = out + (size_t)N_NODES * 3;

    for (int g = blockIdx.x; g < n_groups; g += gridDim.x) {
        const int n16  = g * 64 + wv * 16 + l15;
        const int nc   = (n16 < N_NODES) ? n16 : 0;
        const bool valid = (n16 < N_NODES);

        // B-frags: [h | tot_msg] rows, direct global loads
        bf16x8 b[4];
        #pragma unroll
        for (int s = 0; s < 4; ++s) {
            const float* src = (s < 2) ? (h + (size_t)nc * 64 + s * 32 + l4 * 8)
                                       : (tot_msg + (size_t)nc * 64 + (s - 2) * 32 + l4 * 8);
            const f32x4 f0 = *(const f32x4*)src;
            const f32x4 f1 = *(const f32x4*)(src + 4);
            bf16x8 bv;
            #pragma unroll
            for (int j = 0; j < 4; ++j) { bv[j] = f2bf(f0[j]); bv[4 + j] = f2bf(f1[j]); }
            b[s] = bv;
        }

        #pragma unroll
        for (int t = 0; t < 4; ++t) {
            f32x4 acc = __builtin_amdgcn_mfma_f32_16x16x32_bf16(awn1[t][0], b[0], zf, 0, 0, 0);
            acc = __builtin_amdgcn_mfma_f32_16x16x32_bf16(awn1[t][1], b[1], acc, 0, 0, 0);
            acc = __builtin_amdgcn_mfma_f32_16x16x32_bf16(awn1[t][2], b[2], acc, 0, 0, 0);
            acc = __builtin_amdgcn_mfma_f32_16x16x32_bf16(awn1[t][3], b[3], acc, 0, 0, 0);
            bf16x4 gg;
            #pragma unroll
            for (int r = 0; r < 4; ++r)
                gg[r] = f2bf(silu_f(acc[r] + bn1r4[t][r]));
            *(bf16x4*)&g_s[wv][l15 * 72 + t * 16 + l4 * 4] = gg;
        }
        LDS_FENCE();

        {
            const bf16x8 g0 = *(const bf16x8*)&g_s[wv][l15 * 72 + l4 * 8];
            const bf16x8 g1 = *(const bf16x8*)&g_s[wv][l15 * 72 + 32 + l4 * 8];
            #pragma unroll
            for (int t = 0; t < 4; ++t) {
                f32x4 acc = __builtin_amdgcn_mfma_f32_16x16x32_bf16(awn2[t][0], g0, zf, 0, 0, 0);
                acc = __builtin_amdgcn_mfma_f32_16x16x32_bf16(awn2[t][1], g1, acc, 0, 0, 0);
                if (valid) {
                    f32x4 o;
                    #pragma unroll
                    for (int r = 0; r < 4; ++r) o[r] = acc[r] + bn2r4[t][r];
                    *(f32x4*)&out_h[(size_t)n16 * 64 + t * 16 + l4 * 4] = o;
                }
            }
        }
        LDS_FENCE();

        // x_new = x + clamp(tot_f / max(deg,1), +-100): 48 lanes -> 16 nodes x 3
        if (lane < 48) {
            const int nn = lane / 3;
            const int ci = lane % 3;
            const int n  = g * 64 + wv * 16 + nn;
            if (n < N_NODES) {
                const float tot = totf4[n * 4 + ci];
                const float deg = totf4[n * 4 + 3];
                float v = tot / fmaxf(deg, 1.0f);
                v = fminf(fmaxf(v, -100.0f), 100.0f);
                out[n * 3 + ci] = x[n * 3 + ci] + v;
            }
        }
    }
}

// ---------------------------------------------------------------- launcher
extern "C" void kernel_launch(void* const* d_in, const int* in_sizes, int n_in,
                              void* d_out, int out_size, void* d_ws, size_t ws_size,
                              hipStream_t stream) {
    const float* x        = (const float*)d_in[0];
    const float* h        = (const float*)d_in[1];
    const float* edge_fea = (const float*)d_in[2];
    const float* w1e      = (const float*)d_in[3];
    const float* b1e      = (const float*)d_in[4];
    const float* w2e      = (const float*)d_in[5];
    const float* b2e      = (const float*)d_in[6];
    const float* wc1      = (const float*)d_in[7];
    const float* bc1      = (const float*)d_in[8];
    const float* wc2      = (const float*)d_in[9];
    const float* bc2      = (const float*)d_in[10];
    const float* wn1      = (const float*)d_in[11];
    const float* bn1      = (const float*)d_in[12];
    const float* wn2      = (const float*)d_in[13];
    const float* bn2      = (const float*)d_in[14];
    const int*   row      = (const int*)d_in[15];
    const int*   col      = (const int*)d_in[16];
    float* out = (float*)d_out;

    // ws layout (floats): hA[N*64] | hB[N*64] | tot_msg[N*64] | totf4[N*4]
    float* ws      = (float*)d_ws;
    float* hA      = ws;
    float* hB      = ws + (size_t)N_NODES * 64;
    float* tot_msg = ws + (size_t)2 * N_NODES * 64;
    float* totf4   = ws + (size_t)3 * N_NODES * 64;

    hipMemsetAsync(tot_msg, 0, (size_t)(N_NODES * 64 + N_NODES * 4) * sizeof(float), stream);

    node_pre_kernel<<<256, 256, 0, stream>>>(h, w1e, hA, hB);
    edge_kernel<<<2048, 256, 0, stream>>>(x, edge_fea, w1e, b1e, w2e, b2e,
                                          wc1, bc1, wc2, bc2, row, col,
                                          hA, hB, tot_msg, totf4);
    node_kernel<<<256, 256, 0, stream>>>(x, h, wn1, bn1, wn2, bn2,
                                         tot_msg, totf4, out);
}

// Round 6
// 381.363 us; speedup vs baseline: 2.3307x; 1.0614x over previous
//
#include <hip/hip_runtime.h>
#include <cstddef>

// EGNN layer. Round 6: software-pipelined edge loop.
//  - prefetch idx one group ahead; x/hA/hB/fea gathers for group g+1 issued
//    mid-body of group g (after layer1 frees the state registers)
//  - per-lane idx/x loads (dup lanes coalesce); atomic row idx via __shfl
//  - fea load predicated on l4<2 (was fetched twice -> -51MB FETCH)
//  - weight-staging LDS aliased with activation tile (-9KB LDS)
//  - tot_msg/totf4 zeroing folded into node_pre (no memset dispatch)
//  - edge grid 2500 blocks = exactly 5 groups each (no tail imbalance)
//
// MFMA fragment layouts (gfx950, 16x16x32 bf16, verified learn_hip m89/m91):
//   A: lane holds A[m=lane&15][k=(lane>>4)*8 + j], j=0..7
//   B: lane holds B[k=(lane>>4)*8 + j][n=lane&15]
//   C/D: lane reg r holds D[row=(lane>>4)*4+r][col=lane&15]

#define N_NODES 50000
#define M_EDGES 800000

typedef __attribute__((ext_vector_type(8))) short bf16x8;
typedef __attribute__((ext_vector_type(4))) short bf16x4;
typedef __attribute__((ext_vector_type(4))) float f32x4;

__device__ __forceinline__ float silu_f(float v) {
    return v / (1.0f + __expf(-v));
}

__device__ __forceinline__ short f2bf(float f) {   // RNE float->bf16
    union { float f; unsigned u; } v; v.f = f;
    unsigned r = v.u + 0x7fffu + ((v.u >> 16) & 1u);
    return (short)(r >> 16);
}

__device__ __forceinline__ float bf2f(short s) {
    union { unsigned u; float f; } v;
    v.u = ((unsigned)(unsigned short)s) << 16;
    return v.f;
}

#define LDS_FENCE() __asm__ volatile("" ::: "memory")

// ---------------------------------------------------------------- K1: hA/hB
// Also zero-fills tot_msg and totf4 (replaces hipMemsetAsync dispatch).
__global__ __launch_bounds__(256, 3) void node_pre_kernel(
    const float* __restrict__ h, const float* __restrict__ w1e,
    float* __restrict__ hA, float* __restrict__ hB,
    float* __restrict__ tot_msg, float* __restrict__ totf4)
{
    const int tid  = threadIdx.x;
    const int lane = tid & 63;
    const int wv   = __builtin_amdgcn_readfirstlane(tid >> 6);
    const int l15  = lane & 15;
    const int l4   = lane >> 4;

    bf16x8 wa[4][2], wb[4][2];
    #pragma unroll
    for (int t = 0; t < 4; ++t)
        #pragma unroll
        for (int s = 0; s < 2; ++s) {
            bf16x8 fa, fb;
            #pragma unroll
            for (int j = 0; j < 8; ++j) {
                const int k = s * 32 + l4 * 8 + j;
                fa[j] = f2bf(w1e[(size_t)(1 + k) * 64 + t * 16 + l15]);
                fb[j] = f2bf(w1e[(size_t)(65 + k) * 64 + t * 16 + l15]);
            }
            wa[t][s] = fa; wb[t][s] = fb;
        }

    const f32x4 zf = {0.f, 0.f, 0.f, 0.f};
    const int n_groups = (N_NODES + 63) / 64;

    for (int g = blockIdx.x; g < n_groups; g += gridDim.x) {
        const int n16  = g * 64 + wv * 16 + l15;
        const int nc   = (n16 < N_NODES) ? n16 : 0;
        const bool valid = (n16 < N_NODES);

        const float* hp = h + (size_t)nc * 64;
        bf16x8 bh[2];
        #pragma unroll
        for (int s = 0; s < 2; ++s) {
            const f32x4 f0 = *(const f32x4*)(hp + s * 32 + l4 * 8);
            const f32x4 f1 = *(const f32x4*)(hp + s * 32 + l4 * 8 + 4);
            bf16x8 bv;
            #pragma unroll
            for (int j = 0; j < 4; ++j) { bv[j] = f2bf(f0[j]); bv[4 + j] = f2bf(f1[j]); }
            bh[s] = bv;
        }

        #pragma unroll
        for (int t = 0; t < 4; ++t) {
            f32x4 aA = __builtin_amdgcn_mfma_f32_16x16x32_bf16(wa[t][0], bh[0], zf, 0, 0, 0);
            aA = __builtin_amdgcn_mfma_f32_16x16x32_bf16(wa[t][1], bh[1], aA, 0, 0, 0);
            f32x4 aB = __builtin_amdgcn_mfma_f32_16x16x32_bf16(wb[t][0], bh[0], zf, 0, 0, 0);
            aB = __builtin_amdgcn_mfma_f32_16x16x32_bf16(wb[t][1], bh[1], aB, 0, 0, 0);
            if (valid) {
                *(f32x4*)&hA[(size_t)n16 * 64 + t * 16 + l4 * 4] = aA;
                *(f32x4*)&hB[(size_t)n16 * 64 + t * 16 + l4 * 4] = aB;
                *(f32x4*)&tot_msg[(size_t)n16 * 64 + t * 16 + l4 * 4] = zf;
            }
        }
        if (valid && l4 == 0)
            *(f32x4*)&totf4[(size_t)n16 * 4] = zf;
    }
}

// ---------------------------------------------------------------- K2: edges
__global__ __launch_bounds__(256, 2) void edge_kernel(
    const float* __restrict__ x, const float* __restrict__ edge_fea,
    const float* __restrict__ w1e, const float* __restrict__ b1e,
    const float* __restrict__ w2e, const float* __restrict__ b2e,
    const float* __restrict__ wc1, const float* __restrict__ bc1,
    const float* __restrict__ wc2, const float* __restrict__ bc2,
    const int* __restrict__ row, const int* __restrict__ col,
    const float* __restrict__ hA, const float* __restrict__ hB,
    float* __restrict__ tot_msg, float* __restrict__ totf4)
{
    // wst_s[0] doubles as the per-wave activation tiles after the prologue
    // (4 waves x 16 rows x 72 shorts = 4608 shorts = exactly 64*72).
    __shared__ __align__(16) short wst_s[2][64 * 72];
    __shared__ f32x4 cst_s[5][16];   // b1,w1r0,b2,bc1,wc2 by [t*4+l4]

    const int tid  = threadIdx.x;
    const int lane = tid & 63;
    const int wv   = __builtin_amdgcn_readfirstlane(tid >> 6);
    const int l15  = lane & 15;
    const int l4   = lane >> 4;

    // ---- prologue: stage transposed bf16 weights + constants
    for (int i = tid; i < 4096; i += 256) {
        const int k = i >> 6, n = i & 63;
        wst_s[0][n * 72 + k] = f2bf(w2e[i]);
        wst_s[1][n * 72 + k] = f2bf(wc1[i]);
    }
    if (tid < 16)       cst_s[0][tid]      = *(const f32x4*)(b1e + tid * 4);
    else if (tid < 32)  cst_s[1][tid - 16] = *(const f32x4*)(w1e + (tid - 16) * 4);
    else if (tid < 48)  cst_s[2][tid - 32] = *(const f32x4*)(b2e + (tid - 32) * 4);
    else if (tid < 64)  cst_s[3][tid - 48] = *(const f32x4*)(bc1 + (tid - 48) * 4);
    else if (tid < 80)  cst_s[4][tid - 64] = *(const f32x4*)(wc2 + (tid - 64) * 4);
    __syncthreads();

    bf16x8 bw2f[4][2], bwc1f[4][2], bw1cf[4];
    #pragma unroll
    for (int t = 0; t < 4; ++t) {
        #pragma unroll
        for (int s = 0; s < 2; ++s) {
            bw2f[t][s]  = *(const bf16x8*)&wst_s[0][(t * 16 + l15) * 72 + s * 32 + l4 * 8];
            bwc1f[t][s] = *(const bf16x8*)&wst_s[1][(t * 16 + l15) * 72 + s * 32 + l4 * 8];
        }
        bf16x8 wf;
        #pragma unroll
        for (int b = 0; b < 8; ++b) {
            const int k = l4 * 8 + b;
            wf[b] = (k < 16) ? f2bf(w1e[(size_t)(129 + k) * 64 + t * 16 + l15]) : (short)0;
        }
        bw1cf[t] = wf;
    }
    const float bc2v = bc2[0];
    __syncthreads();   // all frag loads done before wst_s[0] is reused

    short* const us = &wst_s[0][wv * 1152];   // per-wave 16x72 activation tile
    const f32x4 zf = {0.f, 0.f, 0.f, 0.f};

    // ---- pipelined group loop (2500 blocks x exactly 5 groups)
    const int groups = M_EDGES / 64;     // 12500
    const int gstep  = gridDim.x;
    int g = blockIdx.x;

    int   cr;                            // row idx of current (g, l15) edge
    float xr0, xr1, xr2, xc0, xc1, xc2;  // x[row], x[col]
    f32x4 cha[4], chb[4];                // gathered hA/hB (16 ch per lane)
    f32x4 cf0 = zf, cf1 = zf;            // fea halves (l4<2 only)

    auto issue_gathers = [&](int gg, int rI, int cI) {
        const float* xr = x + (size_t)rI * 3;
        const float* xc = x + (size_t)cI * 3;
        xr0 = xr[0]; xr1 = xr[1]; xr2 = xr[2];
        xc0 = xc[0]; xc1 = xc[1]; xc2 = xc[2];
        #pragma unroll
        for (int t = 0; t < 4; ++t) {
            cha[t] = *(const f32x4*)&hA[(size_t)rI * 64 + t * 16 + l4 * 4];
            chb[t] = *(const f32x4*)&hB[(size_t)cI * 64 + t * 16 + l4 * 4];
        }
        if (l4 < 2) {
            const float* fp = edge_fea + (size_t)(gg * 64 + wv * 16 + l15) * 16 + l4 * 8;
            cf0 = *(const f32x4*)fp;
            cf1 = *(const f32x4*)(fp + 4);
        }
    };

    {   // warm-up: idx + gathers for first group
        const int e = g * 64 + wv * 16 + l15;
        const int iaR = row[e], iaC = col[e];
        issue_gathers(g, iaR, iaC);
        cr = iaR;
    }
    int ibR = 0, ibC = 0;                // idx for g+gstep
    {
        const int gn = g + gstep;
        if (gn < groups) { const int e = gn * 64 + wv * 16 + l15; ibR = row[e]; ibC = col[e]; }
    }

    while (true) {
        // ---- geometry (per-lane, from prefetched x)
        const float dx = xr0 - xc0, dy = xr1 - xc1, dz = xr2 - xc2;
        const float sq = dx * dx + dy * dy + dz * dz;

        // ---- fea B-frag from prefetched registers (pad lanes = zero regs)
        bf16x8 bfea;
        {
            bf16x8 tv;
            #pragma unroll
            for (int j = 0; j < 4; ++j) { tv[j] = f2bf(cf0[j]); tv[4 + j] = f2bf(cf1[j]); }
            const bf16x8 zv = {0, 0, 0, 0, 0, 0, 0, 0};
            bfea = (l4 < 2) ? tv : zv;
        }

        // ---- layer1: W1c^T @ fea' + gathered hA/hB + sq*w1r0 + b1 -> u tile
        f32x4 acc1[4];
        #pragma unroll
        for (int t = 0; t < 4; ++t)
            acc1[t] = __builtin_amdgcn_mfma_f32_16x16x32_bf16(bw1cf[t], bfea, zf, 0, 0, 0);
        #pragma unroll
        for (int t = 0; t < 4; ++t) {
            const f32x4 b1v = cst_s[0][t * 4 + l4];
            const f32x4 w0v = cst_s[1][t * 4 + l4];
            bf16x4 uu;
            #pragma unroll
            for (int r = 0; r < 4; ++r) {
                const float pre = acc1[t][r] + cha[t][r] + chb[t][r] + sq * w0v[r] + b1v[r];
                uu[r] = f2bf(silu_f(pre));
            }
            *(bf16x4*)&us[l15 * 72 + t * 16 + l4 * 4] = uu;
        }
        LDS_FENCE();

        // ---- prefetch next group's gathers (state regs are free now)
        const int gn = g + gstep;
        const bool hn = (gn < groups);
        int nrow = cr;
        if (hn) { issue_gathers(gn, ibR, ibC); nrow = ibR; }

        // ---- layer2: msg' = silu(W2^T @ u1' + b2)
        f32x4 acc2[4];
        {
            const bf16x8 a0 = *(const bf16x8*)&us[l15 * 72 + l4 * 8];
            const bf16x8 a1 = *(const bf16x8*)&us[l15 * 72 + 32 + l4 * 8];
            #pragma unroll
            for (int t = 0; t < 4; ++t) {
                acc2[t] = __builtin_amdgcn_mfma_f32_16x16x32_bf16(bw2f[t][0], a0, zf, 0, 0, 0);
                acc2[t] = __builtin_amdgcn_mfma_f32_16x16x32_bf16(bw2f[t][1], a1, acc2[t], 0, 0, 0);
            }
        }
        LDS_FENCE();
        #pragma unroll
        for (int t = 0; t < 4; ++t) {
            const f32x4 b2v = cst_s[2][t * 4 + l4];
            bf16x4 mm;
            #pragma unroll
            for (int r = 0; r < 4; ++r)
                mm[r] = f2bf(silu_f(acc2[t][r] + b2v[r]));
            *(bf16x4*)&us[l15 * 72 + t * 16 + l4 * 4] = mm;
        }
        LDS_FENCE();

        // ---- layer3 MFMAs (issue before atomics so they overlap)
        f32x4 acc3[4];
        {
            const bf16x8 a0 = *(const bf16x8*)&us[l15 * 72 + l4 * 8];
            const bf16x8 a1 = *(const bf16x8*)&us[l15 * 72 + 32 + l4 * 8];
            #pragma unroll
            for (int t = 0; t < 4; ++t) {
                acc3[t] = __builtin_amdgcn_mfma_f32_16x16x32_bf16(bwc1f[t][0], a0, zf, 0, 0, 0);
                acc3[t] = __builtin_amdgcn_mfma_f32_16x16x32_bf16(bwc1f[t][1], a1, acc3[t], 0, 0, 0);
            }
        }

        // ---- tot_msg atomics, coalesced: 4 rows x 16 consecutive channels
        // per instruction. Row index of edge er comes from lane er via shfl.
        #pragma unroll
        for (int r = 0; r < 4; ++r) {
            const int er   = l4 * 4 + r;
            const int rowr = __shfl(cr, er);
            float* const mb = &tot_msg[(size_t)rowr * 64 + l15];
            #pragma unroll
            for (int t = 0; t < 4; ++t) {
                const float mv = bf2f(us[er * 72 + t * 16 + l15]);
                atomicAdd(mb + t * 16, mv);
            }
        }

        // ---- coord head
        float p = 0.f;
        #pragma unroll
        for (int t = 0; t < 4; ++t) {
            const f32x4 bcv = cst_s[3][t * 4 + l4];
            const f32x4 wcv = cst_s[4][t * 4 + l4];
            #pragma unroll
            for (int r = 0; r < 4; ++r)
                p += silu_f(acc3[t][r] + bcv[r]) * wcv[r];
        }
        p += __shfl_xor(p, 16);
        p += __shfl_xor(p, 32);
        const float coord = p + bc2v;

        // ---- totf4 atomic: lane -> (edge=l15, comp=l4)
        const float comp = (l4 == 0) ? dx : (l4 == 1) ? dy : (l4 == 2) ? dz : 0.f;
        const float val  = (l4 == 3) ? 1.0f : comp * coord;
        atomicAdd(&totf4[(size_t)cr * 4 + l4], val);

        if (!hn) break;
        cr = nrow; g = gn;
        {   // idx prefetch for the group after next
            const int g2 = gn + gstep;
            if (g2 < groups) { const int e = g2 * 64 + wv * 16 + l15; ibR = row[e]; ibC = col[e]; }
        }
    }
}

// ---------------------------------------------------------------- K3: nodes
__global__ __launch_bounds__(256, 2) void node_kernel(
    const float* __restrict__ x, const float* __restrict__ h,
    const float* __restrict__ wn1, const float* __restrict__ bn1,
    const float* __restrict__ wn2, const float* __restrict__ bn2,
    const float* __restrict__ tot_msg, const float* __restrict__ totf4,
    float* __restrict__ out)
{
    __shared__ __align__(16) short g_s[4][16 * 72];

    const int tid  = threadIdx.x;
    const int lane = tid & 63;
    const int wv   = __builtin_amdgcn_readfirstlane(tid >> 6);
    const int l15  = lane & 15;
    const int l4   = lane >> 4;

    bf16x8 awn1[4][4], awn2[4][2];
    f32x4 bn1r4[4], bn2r4[4];
    #pragma unroll
    for (int t = 0; t < 4; ++t) {
        #pragma unroll
        for (int s = 0; s < 4; ++s) {
            bf16x8 fv;
            #pragma unroll
            for (int j = 0; j < 8; ++j)
                fv[j] = f2bf(wn1[(size_t)(s * 32 + l4 * 8 + j) * 64 + t * 16 + l15]);
            awn1[t][s] = fv;
        }
        #pragma unroll
        for (int s = 0; s < 2; ++s) {
            bf16x8 fv;
            #pragma unroll
            for (int j = 0; j < 8; ++j)
                fv[j] = f2bf(wn2[(size_t)(s * 32 + l4 * 8 + j) * 64 + t * 16 + l15]);
            awn2[t][s] = fv;
        }
        bn1r4[t] = *(const f32x4*)&bn1[t * 16 + l4 * 4];
        bn2r4[t] = *(const f32x4*)&bn2[t * 16 + l4 * 4];
    }

    const f32x4 zf = {0.f, 0.f, 0.f, 0.f};
    const int n_groups = (N_NODES + 63) / 64;
    float* const out_h = out + (size_t)N_NODES * 3;

    for (int g = blockIdx.x; g < n_groups; g += gridDim.x) {
        const int n16  = g * 64 + wv * 16 + l15;
        const int nc   = (n16 < N_NODES) ? n16 : 0;
        const bool valid = (n16 < N_NODES);

        bf16x8 b[4];
        #pragma unroll
        for (int s = 0; s < 4; ++s) {
            const float* src = (s < 2) ? (h + (size_t)nc * 64 + s * 32 + l4 * 8)
                                       : (tot_msg + (size_t)nc * 64 + (s - 2) * 32 + l4 * 8);
            const f32x4 f0 = *(const f32x4*)src;
            const f32x4 f1 = *(const f32x4*)(src + 4);
            bf16x8 bv;
            #pragma unroll
            for (int j = 0; j < 4; ++j) { bv[j] = f2bf(f0[j]); bv[4 + j] = f2bf(f1[j]); }
            b[s] = bv;
        }

        #pragma unroll
        for (int t = 0; t < 4; ++t) {
            f32x4 acc = __builtin_amdgcn_mfma_f32_16x16x32_bf16(awn1[t][0], b[0], zf, 0, 0, 0);
            acc = __builtin_amdgcn_mfma_f32_16x16x32_bf16(awn1[t][1], b[1], acc, 0, 0, 0);
            acc = __builtin_amdgcn_mfma_f32_16x16x32_bf16(awn1[t][2], b[2], acc, 0, 0, 0);
            acc = __builtin_amdgcn_mfma_f32_16x16x32_bf16(awn1[t][3], b[3], acc, 0, 0, 0);
            bf16x4 gg;
            #pragma unroll
            for (int r = 0; r < 4; ++r)
                gg[r] = f2bf(silu_f(acc[r] + bn1r4[t][r]));
            *(bf16x4*)&g_s[wv][l15 * 72 + t * 16 + l4 * 4] = gg;
        }
        LDS_FENCE();

        {
            const bf16x8 g0 = *(const bf16x8*)&g_s[wv][l15 * 72 + l4 * 8];
            const bf16x8 g1 = *(const bf16x8*)&g_s[wv][l15 * 72 + 32 + l4 * 8];
            #pragma unroll
            for (int t = 0; t < 4; ++t) {
                f32x4 acc = __builtin_amdgcn_mfma_f32_16x16x32_bf16(awn2[t][0], g0, zf, 0, 0, 0);
                acc = __builtin_amdgcn_mfma_f32_16x16x32_bf16(awn2[t][1], g1, acc, 0, 0, 0);
                if (valid) {
                    f32x4 o;
                    #pragma unroll
                    for (int r = 0; r < 4; ++r) o[r] = acc[r] + bn2r4[t][r];
                    *(f32x4*)&out_h[(size_t)n16 * 64 + t * 16 + l4 * 4] = o;
                }
            }
        }
        LDS_FENCE();

        if (lane < 48) {
            const int nn = lane / 3;
            const int ci = lane % 3;
            const int n  = g * 64 + wv * 16 + nn;
            if (n < N_NODES) {
                const float tot = totf4[n * 4 + ci];
                const float deg = totf4[n * 4 + 3];
                float v = tot / fmaxf(deg, 1.0f);
                v = fminf(fmaxf(v, -100.0f), 100.0f);
                out[n * 3 + ci] = x[n * 3 + ci] + v;
            }
        }
    }
}

// ---------------------------------------------------------------- launcher
extern "C" void kernel_launch(void* const* d_in, const int* in_sizes, int n_in,
                              void* d_out, int out_size, void* d_ws, size_t ws_size,
                              hipStream_t stream) {
    const float* x        = (const float*)d_in[0];
    const float* h        = (const float*)d_in[1];
    const float* edge_fea = (const float*)d_in[2];
    const float* w1e      = (const float*)d_in[3];
    const float* b1e      = (const float*)d_in[4];
    const float* w2e      = (const float*)d_in[5];
    const float* b2e      = (const float*)d_in[6];
    const float* wc1      = (const float*)d_in[7];
    const float* bc1      = (const float*)d_in[8];
    const float* wc2      = (const float*)d_in[9];
    const float* bc2      = (const float*)d_in[10];
    const float* wn1      = (const float*)d_in[11];
    const float* bn1      = (const float*)d_in[12];
    const float* wn2      = (const float*)d_in[13];
    const float* bn2      = (const float*)d_in[14];
    const int*   row      = (const int*)d_in[15];
    const int*   col      = (const int*)d_in[16];
    float* out = (float*)d_out;

    // ws layout (floats): hA[N*64] | hB[N*64] | tot_msg[N*64] | totf4[N*4]
    float* ws      = (float*)d_ws;
    float* hA      = ws;
    float* hB      = ws + (size_t)N_NODES * 64;
    float* tot_msg = ws + (size_t)2 * N_NODES * 64;
    float* totf4   = ws + (size_t)3 * N_NODES * 64;

    node_pre_kernel<<<256, 256, 0, stream>>>(h, w1e, hA, hB, tot_msg, totf4);
    edge_kernel<<<2500, 256, 0, stream>>>(x, edge_fea, w1e, b1e, w2e, b2e,
                                          wc1, bc1, wc2, bc2, row, col,
                                          hA, hB, tot_msg, totf4);
    node_kernel<<<256, 256, 0, stream>>>(x, h, wn1, bn1, wn2, bn2,
                                         tot_msg, totf4, out);
}

// Round 7
// 326.863 us; speedup vs baseline: 2.7194x; 1.1667x over previous
//
#include <hip/hip_runtime.h>
#include <cstddef>

// EGNN layer. Round 7: packed-bf16 atomics for tot_msg (halves atomic line
// transactions, the measured wall: r4 tripled lines -> 3x time; r5 restored).
//  - tot_msg is now bf16[N][64]; aggregation via global_atomic_pk_add_bf16
//    (2 ch / lane / instruction; 4 rows x 32 consecutive ch per instruction
//    -> 1 full 64B line per row; 8 instr/group vs 16)
//  - node_kernel loads tot_msg directly as bf16 B-fragments
//  - node_pre zero-fills bf16 tot_msg + totf4
//  - node grids 256 -> 782 blocks (latency-bound kernels get 3x TLP)
//  - everything else = round 6 (pipelined edge loop, coalesced patterns)
//
// MFMA fragment layouts (gfx950, 16x16x32 bf16, verified learn_hip m89/m91):
//   A: lane holds A[m=lane&15][k=(lane>>4)*8 + j], j=0..7
//   B: lane holds B[k=(lane>>4)*8 + j][n=lane&15]
//   C/D: lane reg r holds D[row=(lane>>4)*4+r][col=lane&15]

#define N_NODES 50000
#define M_EDGES 800000

typedef __attribute__((ext_vector_type(8))) short bf16x8;
typedef __attribute__((ext_vector_type(4))) short bf16x4;
typedef __attribute__((ext_vector_type(2))) short bf16x2;
typedef __attribute__((ext_vector_type(4))) float f32x4;

__device__ __forceinline__ float silu_f(float v) {
    return v / (1.0f + __expf(-v));
}

__device__ __forceinline__ short f2bf(float f) {   // RNE float->bf16
    union { float f; unsigned u; } v; v.f = f;
    unsigned r = v.u + 0x7fffu + ((v.u >> 16) & 1u);
    return (short)(r >> 16);
}

// packed bf16x2 atomic add to global (gfx950: global_atomic_pk_add_bf16)
__device__ __forceinline__ void atomic_pk_add_bf16(unsigned short* p, unsigned int packed) {
#if __has_builtin(__builtin_amdgcn_global_atomic_fadd_v2bf16)
    typedef bf16x2 __attribute__((address_space(1))) gbf16x2;
    union { unsigned int u; bf16x2 v; } c; c.u = packed;
    __builtin_amdgcn_global_atomic_fadd_v2bf16((gbf16x2*)(unsigned long long)p, c.v);
#else
    asm volatile("global_atomic_pk_add_bf16 %0, %1, off"
                 :: "v"((unsigned long long)p), "v"(packed) : "memory");
#endif
}

#define LDS_FENCE() __asm__ volatile("" ::: "memory")

// ---------------------------------------------------------------- K1: hA/hB
// Also zero-fills tot_msg (bf16) and totf4 (replaces hipMemsetAsync).
__global__ __launch_bounds__(256, 3) void node_pre_kernel(
    const float* __restrict__ h, const float* __restrict__ w1e,
    float* __restrict__ hA, float* __restrict__ hB,
    unsigned short* __restrict__ tot_msg, float* __restrict__ totf4)
{
    const int tid  = threadIdx.x;
    const int lane = tid & 63;
    const int wv   = __builtin_amdgcn_readfirstlane(tid >> 6);
    const int l15  = lane & 15;
    const int l4   = lane >> 4;

    bf16x8 wa[4][2], wb[4][2];
    #pragma unroll
    for (int t = 0; t < 4; ++t)
        #pragma unroll
        for (int s = 0; s < 2; ++s) {
            bf16x8 fa, fb;
            #pragma unroll
            for (int j = 0; j < 8; ++j) {
                const int k = s * 32 + l4 * 8 + j;
                fa[j] = f2bf(w1e[(size_t)(1 + k) * 64 + t * 16 + l15]);
                fb[j] = f2bf(w1e[(size_t)(65 + k) * 64 + t * 16 + l15]);
            }
            wa[t][s] = fa; wb[t][s] = fb;
        }

    const f32x4 zf = {0.f, 0.f, 0.f, 0.f};
    const int n_groups = (N_NODES + 63) / 64;

    for (int g = blockIdx.x; g < n_groups; g += gridDim.x) {
        const int n16  = g * 64 + wv * 16 + l15;
        const int nc   = (n16 < N_NODES) ? n16 : 0;
        const bool valid = (n16 < N_NODES);

        const float* hp = h + (size_t)nc * 64;
        bf16x8 bh[2];
        #pragma unroll
        for (int s = 0; s < 2; ++s) {
            const f32x4 f0 = *(const f32x4*)(hp + s * 32 + l4 * 8);
            const f32x4 f1 = *(const f32x4*)(hp + s * 32 + l4 * 8 + 4);
            bf16x8 bv;
            #pragma unroll
            for (int j = 0; j < 4; ++j) { bv[j] = f2bf(f0[j]); bv[4 + j] = f2bf(f1[j]); }
            bh[s] = bv;
        }

        #pragma unroll
        for (int t = 0; t < 4; ++t) {
            f32x4 aA = __builtin_amdgcn_mfma_f32_16x16x32_bf16(wa[t][0], bh[0], zf, 0, 0, 0);
            aA = __builtin_amdgcn_mfma_f32_16x16x32_bf16(wa[t][1], bh[1], aA, 0, 0, 0);
            f32x4 aB = __builtin_amdgcn_mfma_f32_16x16x32_bf16(wb[t][0], bh[0], zf, 0, 0, 0);
            aB = __builtin_amdgcn_mfma_f32_16x16x32_bf16(wb[t][1], bh[1], aB, 0, 0, 0);
            if (valid) {
                *(f32x4*)&hA[(size_t)n16 * 64 + t * 16 + l4 * 4] = aA;
                *(f32x4*)&hB[(size_t)n16 * 64 + t * 16 + l4 * 4] = aB;
                *(uint2*)&tot_msg[(size_t)n16 * 64 + t * 16 + l4 * 4] = make_uint2(0u, 0u);
            }
        }
        if (valid && l4 == 0)
            *(f32x4*)&totf4[(size_t)n16 * 4] = zf;
    }
}

// ---------------------------------------------------------------- K2: edges
__global__ __launch_bounds__(256, 2) void edge_kernel(
    const float* __restrict__ x, const float* __restrict__ edge_fea,
    const float* __restrict__ w1e, const float* __restrict__ b1e,
    const float* __restrict__ w2e, const float* __restrict__ b2e,
    const float* __restrict__ wc1, const float* __restrict__ bc1,
    const float* __restrict__ wc2, const float* __restrict__ bc2,
    const int* __restrict__ row, const int* __restrict__ col,
    const float* __restrict__ hA, const float* __restrict__ hB,
    unsigned short* __restrict__ tot_msg, float* __restrict__ totf4)
{
    // wst_s[0] doubles as the per-wave activation tiles after the prologue.
    __shared__ __align__(16) short wst_s[2][64 * 72];
    __shared__ f32x4 cst_s[5][16];   // b1,w1r0,b2,bc1,wc2 by [t*4+l4]

    const int tid  = threadIdx.x;
    const int lane = tid & 63;
    const int wv   = __builtin_amdgcn_readfirstlane(tid >> 6);
    const int l15  = lane & 15;
    const int l4   = lane >> 4;

    // ---- prologue: stage transposed bf16 weights + constants
    for (int i = tid; i < 4096; i += 256) {
        const int k = i >> 6, n = i & 63;
        wst_s[0][n * 72 + k] = f2bf(w2e[i]);
        wst_s[1][n * 72 + k] = f2bf(wc1[i]);
    }
    if (tid < 16)       cst_s[0][tid]      = *(const f32x4*)(b1e + tid * 4);
    else if (tid < 32)  cst_s[1][tid - 16] = *(const f32x4*)(w1e + (tid - 16) * 4);
    else if (tid < 48)  cst_s[2][tid - 32] = *(const f32x4*)(b2e + (tid - 32) * 4);
    else if (tid < 64)  cst_s[3][tid - 48] = *(const f32x4*)(bc1 + (tid - 48) * 4);
    else if (tid < 80)  cst_s[4][tid - 64] = *(const f32x4*)(wc2 + (tid - 64) * 4);
    __syncthreads();

    bf16x8 bw2f[4][2], bwc1f[4][2], bw1cf[4];
    #pragma unroll
    for (int t = 0; t < 4; ++t) {
        #pragma unroll
        for (int s = 0; s < 2; ++s) {
            bw2f[t][s]  = *(const bf16x8*)&wst_s[0][(t * 16 + l15) * 72 + s * 32 + l4 * 8];
            bwc1f[t][s] = *(const bf16x8*)&wst_s[1][(t * 16 + l15) * 72 + s * 32 + l4 * 8];
        }
        bf16x8 wf;
        #pragma unroll
        for (int b = 0; b < 8; ++b) {
            const int k = l4 * 8 + b;
            wf[b] = (k < 16) ? f2bf(w1e[(size_t)(129 + k) * 64 + t * 16 + l15]) : (short)0;
        }
        bw1cf[t] = wf;
    }
    const float bc2v = bc2[0];
    __syncthreads();   // all frag loads done before wst_s[0] is reused

    short* const us = &wst_s[0][wv * 1152];   // per-wave 16x72 activation tile
    const f32x4 zf = {0.f, 0.f, 0.f, 0.f};

    // ---- pipelined group loop
    const int groups = M_EDGES / 64;     // 12500
    const int gstep  = gridDim.x;
    int g = blockIdx.x;

    int   cr;
    float xr0, xr1, xr2, xc0, xc1, xc2;
    f32x4 cha[4], chb[4];
    f32x4 cf0 = zf, cf1 = zf;

    auto issue_gathers = [&](int gg, int rI, int cI) {
        const float* xr = x + (size_t)rI * 3;
        const float* xc = x + (size_t)cI * 3;
        xr0 = xr[0]; xr1 = xr[1]; xr2 = xr[2];
        xc0 = xc[0]; xc1 = xc[1]; xc2 = xc[2];
        #pragma unroll
        for (int t = 0; t < 4; ++t) {
            cha[t] = *(const f32x4*)&hA[(size_t)rI * 64 + t * 16 + l4 * 4];
            chb[t] = *(const f32x4*)&hB[(size_t)cI * 64 + t * 16 + l4 * 4];
        }
        if (l4 < 2) {
            const float* fp = edge_fea + (size_t)(gg * 64 + wv * 16 + l15) * 16 + l4 * 8;
            cf0 = *(const f32x4*)fp;
            cf1 = *(const f32x4*)(fp + 4);
        }
    };

    {   // warm-up
        const int e = g * 64 + wv * 16 + l15;
        const int iaR = row[e], iaC = col[e];
        issue_gathers(g, iaR, iaC);
        cr = iaR;
    }
    int ibR = 0, ibC = 0;
    {
        const int gn = g + gstep;
        if (gn < groups) { const int e = gn * 64 + wv * 16 + l15; ibR = row[e]; ibC = col[e]; }
    }

    while (true) {
        const float dx = xr0 - xc0, dy = xr1 - xc1, dz = xr2 - xc2;
        const float sq = dx * dx + dy * dy + dz * dz;

        bf16x8 bfea;
        {
            bf16x8 tv;
            #pragma unroll
            for (int j = 0; j < 4; ++j) { tv[j] = f2bf(cf0[j]); tv[4 + j] = f2bf(cf1[j]); }
            const bf16x8 zv = {0, 0, 0, 0, 0, 0, 0, 0};
            bfea = (l4 < 2) ? tv : zv;
        }

        // ---- layer1
        f32x4 acc1[4];
        #pragma unroll
        for (int t = 0; t < 4; ++t)
            acc1[t] = __builtin_amdgcn_mfma_f32_16x16x32_bf16(bw1cf[t], bfea, zf, 0, 0, 0);
        #pragma unroll
        for (int t = 0; t < 4; ++t) {
            const f32x4 b1v = cst_s[0][t * 4 + l4];
            const f32x4 w0v = cst_s[1][t * 4 + l4];
            bf16x4 uu;
            #pragma unroll
            for (int r = 0; r < 4; ++r) {
                const float pre = acc1[t][r] + cha[t][r] + chb[t][r] + sq * w0v[r] + b1v[r];
                uu[r] = f2bf(silu_f(pre));
            }
            *(bf16x4*)&us[l15 * 72 + t * 16 + l4 * 4] = uu;
        }
        LDS_FENCE();

        // ---- prefetch next group's gathers
        const int gn = g + gstep;
        const bool hn = (gn < groups);
        int nrow = cr;
        if (hn) { issue_gathers(gn, ibR, ibC); nrow = ibR; }

        // ---- layer2
        f32x4 acc2[4];
        {
            const bf16x8 a0 = *(const bf16x8*)&us[l15 * 72 + l4 * 8];
            const bf16x8 a1 = *(const bf16x8*)&us[l15 * 72 + 32 + l4 * 8];
            #pragma unroll
            for (int t = 0; t < 4; ++t) {
                acc2[t] = __builtin_amdgcn_mfma_f32_16x16x32_bf16(bw2f[t][0], a0, zf, 0, 0, 0);
                acc2[t] = __builtin_amdgcn_mfma_f32_16x16x32_bf16(bw2f[t][1], a1, acc2[t], 0, 0, 0);
            }
        }
        LDS_FENCE();
        #pragma unroll
        for (int t = 0; t < 4; ++t) {
            const f32x4 b2v = cst_s[2][t * 4 + l4];
            bf16x4 mm;
            #pragma unroll
            for (int r = 0; r < 4; ++r)
                mm[r] = f2bf(silu_f(acc2[t][r] + b2v[r]));
            *(bf16x4*)&us[l15 * 72 + t * 16 + l4 * 4] = mm;
        }
        LDS_FENCE();

        // ---- layer3 MFMAs (issue before atomics so they overlap)
        f32x4 acc3[4];
        {
            const bf16x8 a0 = *(const bf16x8*)&us[l15 * 72 + l4 * 8];
            const bf16x8 a1 = *(const bf16x8*)&us[l15 * 72 + 32 + l4 * 8];
            #pragma unroll
            for (int t = 0; t < 4; ++t) {
                acc3[t] = __builtin_amdgcn_mfma_f32_16x16x32_bf16(bwc1f[t][0], a0, zf, 0, 0, 0);
                acc3[t] = __builtin_amdgcn_mfma_f32_16x16x32_bf16(bwc1f[t][1], a1, acc3[t], 0, 0, 0);
            }
        }

        // ---- tot_msg atomics, packed bf16x2, coalesced:
        // per instruction: 4 rows (l4) x 32 consecutive channels (l15*2) ->
        // one full 64B line per row. 8 instructions per 16-edge group.
        #pragma unroll
        for (int r = 0; r < 4; ++r) {
            const int er   = l4 * 4 + r;
            const int rowr = __shfl(cr, er);
            unsigned short* const mb = tot_msg + (size_t)rowr * 64;
            #pragma unroll
            for (int t = 0; t < 2; ++t) {
                const unsigned int pk = *(const unsigned int*)&us[er * 72 + t * 32 + l15 * 2];
                atomic_pk_add_bf16(mb + t * 32 + l15 * 2, pk);
            }
        }

        // ---- coord head
        float p = 0.f;
        #pragma unroll
        for (int t = 0; t < 4; ++t) {
            const f32x4 bcv = cst_s[3][t * 4 + l4];
            const f32x4 wcv = cst_s[4][t * 4 + l4];
            #pragma unroll
            for (int r = 0; r < 4; ++r)
                p += silu_f(acc3[t][r] + bcv[r]) * wcv[r];
        }
        p += __shfl_xor(p, 16);
        p += __shfl_xor(p, 32);
        const float coord = p + bc2v;

        const float comp = (l4 == 0) ? dx : (l4 == 1) ? dy : (l4 == 2) ? dz : 0.f;
        const float val  = (l4 == 3) ? 1.0f : comp * coord;
        atomicAdd(&totf4[(size_t)cr * 4 + l4], val);

        if (!hn) break;
        cr = nrow; g = gn;
        {
            const int g2 = gn + gstep;
            if (g2 < groups) { const int e = g2 * 64 + wv * 16 + l15; ibR = row[e]; ibC = col[e]; }
        }
    }
}

// ---------------------------------------------------------------- K3: nodes
__global__ __launch_bounds__(256, 2) void node_kernel(
    const float* __restrict__ x, const float* __restrict__ h,
    const float* __restrict__ wn1, const float* __restrict__ bn1,
    const float* __restrict__ wn2, const float* __restrict__ bn2,
    const unsigned short* __restrict__ tot_msg, const float* __restrict__ totf4,
    float* __restrict__ out)
{
    __shared__ __align__(16) short g_s[4][16 * 72];

    const int tid  = threadIdx.x;
    const int lane = tid & 63;
    const int wv   = __builtin_amdgcn_readfirstlane(tid >> 6);
    const int l15  = lane & 15;
    const int l4   = lane >> 4;

    bf16x8 awn1[4][4], awn2[4][2];
    f32x4 bn1r4[4], bn2r4[4];
    #pragma unroll
    for (int t = 0; t < 4; ++t) {
        #pragma unroll
        for (int s = 0; s < 4; ++s) {
            bf16x8 fv;
            #pragma unroll
            for (int j = 0; j < 8; ++j)
                fv[j] = f2bf(wn1[(size_t)(s * 32 + l4 * 8 + j) * 64 + t * 16 + l15]);
            awn1[t][s] = fv;
        }
        #pragma unroll
        for (int s = 0; s < 2; ++s) {
            bf16x8 fv;
            #pragma unroll
            for (int j = 0; j < 8; ++j)
                fv[j] = f2bf(wn2[(size_t)(s * 32 + l4 * 8 + j) * 64 + t * 16 + l15]);
            awn2[t][s] = fv;
        }
        bn1r4[t] = *(const f32x4*)&bn1[t * 16 + l4 * 4];
        bn2r4[t] = *(const f32x4*)&bn2[t * 16 + l4 * 4];
    }

    const f32x4 zf = {0.f, 0.f, 0.f, 0.f};
    const int n_groups = (N_NODES + 63) / 64;
    float* const out_h = out + (size_t)N_NODES * 3;

    for (int g = blockIdx.x; g < n_groups; g += gridDim.x) {
        const int n16  = g * 64 + wv * 16 + l15;
        const int nc   = (n16 < N_NODES) ? n16 : 0;
        const bool valid = (n16 < N_NODES);

        bf16x8 b[4];
        #pragma unroll
        for (int s = 0; s < 2; ++s) {
            const float* src = h + (size_t)nc * 64 + s * 32 + l4 * 8;
            const f32x4 f0 = *(const f32x4*)src;
            const f32x4 f1 = *(const f32x4*)(src + 4);
            bf16x8 bv;
            #pragma unroll
            for (int j = 0; j < 4; ++j) { bv[j] = f2bf(f0[j]); bv[4 + j] = f2bf(f1[j]); }
            b[s] = bv;
        }
        // tot_msg is already bf16: direct 16B B-frag loads
        b[2] = *(const bf16x8*)(tot_msg + (size_t)nc * 64 + l4 * 8);
        b[3] = *(const bf16x8*)(tot_msg + (size_t)nc * 64 + 32 + l4 * 8);

        #pragma unroll
        for (int t = 0; t < 4; ++t) {
            f32x4 acc = __builtin_amdgcn_mfma_f32_16x16x32_bf16(awn1[t][0], b[0], zf, 0, 0, 0);
            acc = __builtin_amdgcn_mfma_f32_16x16x32_bf16(awn1[t][1], b[1], acc, 0, 0, 0);
            acc = __builtin_amdgcn_mfma_f32_16x16x32_bf16(awn1[t][2], b[2], acc, 0, 0, 0);
            acc = __builtin_amdgcn_mfma_f32_16x16x32_bf16(awn1[t][3], b[3], acc, 0, 0, 0);
            bf16x4 gg;
            #pragma unroll
            for (int r = 0; r < 4; ++r)
                gg[r] = f2bf(silu_f(acc[r] + bn1r4[t][r]));
            *(bf16x4*)&g_s[wv][l15 * 72 + t * 16 + l4 * 4] = gg;
        }
        LDS_FENCE();

        {
            const bf16x8 g0 = *(const bf16x8*)&g_s[wv][l15 * 72 + l4 * 8];
            const bf16x8 g1 = *(const bf16x8*)&g_s[wv][l15 * 72 + 32 + l4 * 8];
            #pragma unroll
            for (int t = 0; t < 4; ++t) {
                f32x4 acc = __builtin_amdgcn_mfma_f32_16x16x32_bf16(awn2[t][0], g0, zf, 0, 0, 0);
                acc = __builtin_amdgcn_mfma_f32_16x16x32_bf16(awn2[t][1], g1, acc, 0, 0, 0);
                if (valid) {
                    f32x4 o;
                    #pragma unroll
                    for (int r = 0; r < 4; ++r) o[r] = acc[r] + bn2r4[t][r];
                    *(f32x4*)&out_h[(size_t)n16 * 64 + t * 16 + l4 * 4] = o;
                }
            }
        }
        LDS_FENCE();

        if (lane < 48) {
            const int nn = lane / 3;
            const int ci = lane % 3;
            const int n  = g * 64 + wv * 16 + nn;
            if (n < N_NODES) {
                const float tot = totf4[n * 4 + ci];
                const float deg = totf4[n * 4 + 3];
                float v = tot / fmaxf(deg, 1.0f);
                v = fminf(fmaxf(v, -100.0f), 100.0f);
                out[n * 3 + ci] = x[n * 3 + ci] + v;
            }
        }
    }
}

// ---------------------------------------------------------------- launcher
extern "C" void kernel_launch(void* const* d_in, const int* in_sizes, int n_in,
                              void* d_out, int out_size, void* d_ws, size_t ws_size,
                              hipStream_t stream) {
    const float* x        = (const float*)d_in[0];
    const float* h        = (const float*)d_in[1];
    const float* edge_fea = (const float*)d_in[2];
    const float* w1e      = (const float*)d_in[3];
    const float* b1e      = (const float*)d_in[4];
    const float* w2e      = (const float*)d_in[5];
    const float* b2e      = (const float*)d_in[6];
    const float* wc1      = (const float*)d_in[7];
    const float* bc1      = (const float*)d_in[8];
    const float* wc2      = (const float*)d_in[9];
    const float* bc2      = (const float*)d_in[10];
    const float* wn1      = (const float*)d_in[11];
    const float* bn1      = (const float*)d_in[12];
    const float* wn2      = (const float*)d_in[13];
    const float* bn2      = (const float*)d_in[14];
    const int*   row      = (const int*)d_in[15];
    const int*   col      = (const int*)d_in[16];
    float* out = (float*)d_out;

    // ws layout: hA f32[N*64] | hB f32[N*64] | totf4 f32[N*4] | tot_msg bf16[N*64]
    float* ws      = (float*)d_ws;
    float* hA      = ws;
    float* hB      = ws + (size_t)N_NODES * 64;
    float* totf4   = ws + (size_t)2 * N_NODES * 64;
    unsigned short* tot_msg = (unsigned short*)(ws + (size_t)2 * N_NODES * 64 + (size_t)N_NODES * 4);

    node_pre_kernel<<<782, 256, 0, stream>>>(h, w1e, hA, hB, tot_msg, totf4);
    edge_kernel<<<2500, 256, 0, stream>>>(x, edge_fea, w1e, b1e, w2e, b2e,
                                          wc1, bc1, wc2, bc2, row, col,
                                          hA, hB, tot_msg, totf4);
    node_kernel<<<782, 256, 0, stream>>>(x, h, wn1, bn1, wn2, bn2,
                                         tot_msg, totf4, out);
}

// Round 8
// 295.824 us; speedup vs baseline: 3.0047x; 1.1049x over previous
//
#include <hip/hip_runtime.h>
#include <cstddef>

// EGNN layer. Round 8: weight fragments pre-converted once (prep_weights),
// killing the per-block scalar-load+convert prologues that dominated the
// node kernels (782 blocks x 1 group each => prologue was ~8x the work).
//  - prep_weights: 60 fragments (wa,wb,w1c,w2,wc1,wn1,wn2) -> bf16 [frag][lane]
//    layout in ws; consumers load each frag as ONE coalesced 16B vector load
//  - edge_kernel: no weight LDS staging, no weight syncthreads; LDS = 10.5KB
//  - everything else = round 7 (pk_add_bf16 tot_msg, pipelined edge loop)
//
// MFMA fragment layouts (gfx950, 16x16x32 bf16, verified learn_hip m89/m91):
//   A: lane holds A[m=lane&15][k=(lane>>4)*8 + j], j=0..7
//   B: lane holds B[k=(lane>>4)*8 + j][n=lane&15]
//   C/D: lane reg r holds D[row=(lane>>4)*4+r][col=lane&15]

#define N_NODES 50000
#define M_EDGES 800000

typedef __attribute__((ext_vector_type(8))) short bf16x8;
typedef __attribute__((ext_vector_type(4))) short bf16x4;
typedef __attribute__((ext_vector_type(2))) short bf16x2;
typedef __attribute__((ext_vector_type(4))) float f32x4;

// fragment array ids (each frag = 64 lanes x 8 shorts = 512 shorts)
#define FR_WA   0    // w1e rows 1..64    [t*2+s], 8 frags
#define FR_WB   8    // w1e rows 65..128  [t*2+s], 8 frags
#define FR_W1C  16   // w1e rows 129..144 (K-pad to 32) [t], 4 frags
#define FR_W2   20   // w2e [t*2+s], 8 frags
#define FR_WC1  28   // wc1 [t*2+s], 8 frags
#define FR_WN1  36   // wn1 (K=128) [t*4+s], 16 frags
#define FR_WN2  52   // wn2 [t*2+s], 8 frags
#define FR_TOTAL 60

__device__ __forceinline__ float silu_f(float v) {
    return v / (1.0f + __expf(-v));
}

__device__ __forceinline__ short f2bf(float f) {   // RNE float->bf16
    union { float f; unsigned u; } v; v.f = f;
    unsigned r = v.u + 0x7fffu + ((v.u >> 16) & 1u);
    return (short)(r >> 16);
}

// packed bf16x2 atomic add to global (gfx950: global_atomic_pk_add_bf16)
__device__ __forceinline__ void atomic_pk_add_bf16(unsigned short* p, unsigned int packed) {
#if __has_builtin(__builtin_amdgcn_global_atomic_fadd_v2bf16)
    typedef bf16x2 __attribute__((address_space(1))) gbf16x2;
    union { unsigned int u; bf16x2 v; } c; c.u = packed;
    __builtin_amdgcn_global_atomic_fadd_v2bf16((gbf16x2*)(unsigned long long)p, c.v);
#else
    asm volatile("global_atomic_pk_add_bf16 %0, %1, off"
                 :: "v"((unsigned long long)p), "v"(packed) : "memory");
#endif
}

#define LDS_FENCE() __asm__ volatile("" ::: "memory")

__device__ __forceinline__ bf16x8 load_frag(const unsigned short* wfrag, int f, int lane) {
    return *(const bf16x8*)(wfrag + (size_t)f * 512 + lane * 8);
}

// ---------------------------------------------------------------- K0: prep
__global__ __launch_bounds__(256) void prep_weights(
    const float* __restrict__ w1e, const float* __restrict__ w2e,
    const float* __restrict__ wc1, const float* __restrict__ wn1,
    const float* __restrict__ wn2, unsigned short* __restrict__ wfrag)
{
    const int gid = blockIdx.x * 256 + threadIdx.x;
    if (gid >= FR_TOTAL * 64) return;
    const int frag = gid >> 6, lane = gid & 63;
    const int l15 = lane & 15, l4 = lane >> 4;

    const float* src; int k0, t; bool pad16 = false;
    if (frag < FR_WB)        { const int f = frag - FR_WA;  t = f >> 1; src = w1e; k0 = 1 + (f & 1) * 32; }
    else if (frag < FR_W1C)  { const int f = frag - FR_WB;  t = f >> 1; src = w1e; k0 = 65 + (f & 1) * 32; }
    else if (frag < FR_W2)   { t = frag - FR_W1C; src = w1e; k0 = 129; pad16 = true; }
    else if (frag < FR_WC1)  { const int f = frag - FR_W2;  t = f >> 1; src = w2e; k0 = (f & 1) * 32; }
    else if (frag < FR_WN1)  { const int f = frag - FR_WC1; t = f >> 1; src = wc1; k0 = (f & 1) * 32; }
    else if (frag < FR_WN2)  { const int f = frag - FR_WN1; t = f >> 2; src = wn1; k0 = (f & 3) * 32; }
    else                     { const int f = frag - FR_WN2; t = f >> 1; src = wn2; k0 = (f & 1) * 32; }
    const int col = t * 16 + l15;

    bf16x8 v;
    #pragma unroll
    for (int j = 0; j < 8; ++j) {
        const int k = l4 * 8 + j;
        const float x = (pad16 && k >= 16) ? 0.f : src[(size_t)(k0 + k) * 64 + col];
        v[j] = f2bf(x);
    }
    *(bf16x8*)(wfrag + (size_t)frag * 512 + lane * 8) = v;
}

// ---------------------------------------------------------------- K1: hA/hB
// Also zero-fills tot_msg (bf16) and totf4.
__global__ __launch_bounds__(256, 3) void node_pre_kernel(
    const float* __restrict__ h, const unsigned short* __restrict__ wfrag,
    float* __restrict__ hA, float* __restrict__ hB,
    unsigned short* __restrict__ tot_msg, float* __restrict__ totf4)
{
    const int tid  = threadIdx.x;
    const int lane = tid & 63;
    const int wv   = __builtin_amdgcn_readfirstlane(tid >> 6);
    const int l15  = lane & 15;
    const int l4   = lane >> 4;

    bf16x8 wa[4][2], wb[4][2];
    #pragma unroll
    for (int t = 0; t < 4; ++t)
        #pragma unroll
        for (int s = 0; s < 2; ++s) {
            wa[t][s] = load_frag(wfrag, FR_WA + t * 2 + s, lane);
            wb[t][s] = load_frag(wfrag, FR_WB + t * 2 + s, lane);
        }

    const f32x4 zf = {0.f, 0.f, 0.f, 0.f};
    const int n_groups = (N_NODES + 63) / 64;

    for (int g = blockIdx.x; g < n_groups; g += gridDim.x) {
        const int n16  = g * 64 + wv * 16 + l15;
        const int nc   = (n16 < N_NODES) ? n16 : 0;
        const bool valid = (n16 < N_NODES);

        const float* hp = h + (size_t)nc * 64;
        bf16x8 bh[2];
        #pragma unroll
        for (int s = 0; s < 2; ++s) {
            const f32x4 f0 = *(const f32x4*)(hp + s * 32 + l4 * 8);
            const f32x4 f1 = *(const f32x4*)(hp + s * 32 + l4 * 8 + 4);
            bf16x8 bv;
            #pragma unroll
            for (int j = 0; j < 4; ++j) { bv[j] = f2bf(f0[j]); bv[4 + j] = f2bf(f1[j]); }
            bh[s] = bv;
        }

        #pragma unroll
        for (int t = 0; t < 4; ++t) {
            f32x4 aA = __builtin_amdgcn_mfma_f32_16x16x32_bf16(wa[t][0], bh[0], zf, 0, 0, 0);
            aA = __builtin_amdgcn_mfma_f32_16x16x32_bf16(wa[t][1], bh[1], aA, 0, 0, 0);
            f32x4 aB = __builtin_amdgcn_mfma_f32_16x16x32_bf16(wb[t][0], bh[0], zf, 0, 0, 0);
            aB = __builtin_amdgcn_mfma_f32_16x16x32_bf16(wb[t][1], bh[1], aB, 0, 0, 0);
            if (valid) {
                *(f32x4*)&hA[(size_t)n16 * 64 + t * 16 + l4 * 4] = aA;
                *(f32x4*)&hB[(size_t)n16 * 64 + t * 16 + l4 * 4] = aB;
                *(uint2*)&tot_msg[(size_t)n16 * 64 + t * 16 + l4 * 4] = make_uint2(0u, 0u);
            }
        }
        if (valid && l4 == 0)
            *(f32x4*)&totf4[(size_t)n16 * 4] = zf;
    }
}

// ---------------------------------------------------------------- K2: edges
__global__ __launch_bounds__(256, 2) void edge_kernel(
    const float* __restrict__ x, const float* __restrict__ edge_fea,
    const float* __restrict__ w1e, const float* __restrict__ b1e,
    const float* __restrict__ b2e, const float* __restrict__ bc1,
    const float* __restrict__ wc2, const float* __restrict__ bc2,
    const int* __restrict__ row, const int* __restrict__ col,
    const float* __restrict__ hA, const float* __restrict__ hB,
    const unsigned short* __restrict__ wfrag,
    unsigned short* __restrict__ tot_msg, float* __restrict__ totf4)
{
    __shared__ __align__(16) short u_s[4][16 * 72];  // per-wave activation tile
    __shared__ f32x4 cst_s[5][16];   // b1,w1r0,b2,bc1,wc2 by [t*4+l4]

    const int tid  = threadIdx.x;
    const int lane = tid & 63;
    const int wv   = __builtin_amdgcn_readfirstlane(tid >> 6);
    const int l15  = lane & 15;
    const int l4   = lane >> 4;

    // ---- constants to LDS (once per block)
    if (tid < 16)       cst_s[0][tid]      = *(const f32x4*)(b1e + tid * 4);
    else if (tid < 32)  cst_s[1][tid - 16] = *(const f32x4*)(w1e + (tid - 16) * 4);
    else if (tid < 48)  cst_s[2][tid - 32] = *(const f32x4*)(b2e + (tid - 32) * 4);
    else if (tid < 64)  cst_s[3][tid - 48] = *(const f32x4*)(bc1 + (tid - 48) * 4);
    else if (tid < 80)  cst_s[4][tid - 64] = *(const f32x4*)(wc2 + (tid - 64) * 4);

    // ---- weight fragments: direct coalesced 16B loads from prepped global
    bf16x8 bw2f[4][2], bwc1f[4][2], bw1cf[4];
    #pragma unroll
    for (int t = 0; t < 4; ++t) {
        #pragma unroll
        for (int s = 0; s < 2; ++s) {
            bw2f[t][s]  = load_frag(wfrag, FR_W2  + t * 2 + s, lane);
            bwc1f[t][s] = load_frag(wfrag, FR_WC1 + t * 2 + s, lane);
        }
        bw1cf[t] = load_frag(wfrag, FR_W1C + t, lane);
    }
    const float bc2v = bc2[0];
    __syncthreads();

    short* const us = &u_s[wv][0];
    const f32x4 zf = {0.f, 0.f, 0.f, 0.f};

    // ---- pipelined group loop
    const int groups = M_EDGES / 64;     // 12500
    const int gstep  = gridDim.x;
    int g = blockIdx.x;

    int   cr;
    float xr0, xr1, xr2, xc0, xc1, xc2;
    f32x4 cha[4], chb[4];
    f32x4 cf0 = zf, cf1 = zf;

    auto issue_gathers = [&](int gg, int rI, int cI) {
        const float* xr = x + (size_t)rI * 3;
        const float* xc = x + (size_t)cI * 3;
        xr0 = xr[0]; xr1 = xr[1]; xr2 = xr[2];
        xc0 = xc[0]; xc1 = xc[1]; xc2 = xc[2];
        #pragma unroll
        for (int t = 0; t < 4; ++t) {
            cha[t] = *(const f32x4*)&hA[(size_t)rI * 64 + t * 16 + l4 * 4];
            chb[t] = *(const f32x4*)&hB[(size_t)cI * 64 + t * 16 + l4 * 4];
        }
        if (l4 < 2) {
            const float* fp = edge_fea + (size_t)(gg * 64 + wv * 16 + l15) * 16 + l4 * 8;
            cf0 = *(const f32x4*)fp;
            cf1 = *(const f32x4*)(fp + 4);
        }
    };

    {   // warm-up
        const int e = g * 64 + wv * 16 + l15;
        const int iaR = row[e], iaC = col[e];
        issue_gathers(g, iaR, iaC);
        cr = iaR;
    }
    int ibR = 0, ibC = 0;
    {
        const int gn = g + gstep;
        if (gn < groups) { const int e = gn * 64 + wv * 16 + l15; ibR = row[e]; ibC = col[e]; }
    }

    while (true) {
        const float dx = xr0 - xc0, dy = xr1 - xc1, dz = xr2 - xc2;
        const float sq = dx * dx + dy * dy + dz * dz;

        bf16x8 bfea;
        {
            bf16x8 tv;
            #pragma unroll
            for (int j = 0; j < 4; ++j) { tv[j] = f2bf(cf0[j]); tv[4 + j] = f2bf(cf1[j]); }
            const bf16x8 zv = {0, 0, 0, 0, 0, 0, 0, 0};
            bfea = (l4 < 2) ? tv : zv;
        }

        // ---- layer1
        f32x4 acc1[4];
        #pragma unroll
        for (int t = 0; t < 4; ++t)
            acc1[t] = __builtin_amdgcn_mfma_f32_16x16x32_bf16(bw1cf[t], bfea, zf, 0, 0, 0);
        #pragma unroll
        for (int t = 0; t < 4; ++t) {
            const f32x4 b1v = cst_s[0][t * 4 + l4];
            const f32x4 w0v = cst_s[1][t * 4 + l4];
            bf16x4 uu;
            #pragma unroll
            for (int r = 0; r < 4; ++r) {
                const float pre = acc1[t][r] + cha[t][r] + chb[t][r] + sq * w0v[r] + b1v[r];
                uu[r] = f2bf(silu_f(pre));
            }
            *(bf16x4*)&us[l15 * 72 + t * 16 + l4 * 4] = uu;
        }
        LDS_FENCE();

        // ---- prefetch next group's gathers
        const int gn = g + gstep;
        const bool hn = (gn < groups);
        int nrow = cr;
        if (hn) { issue_gathers(gn, ibR, ibC); nrow = ibR; }

        // ---- layer2
        f32x4 acc2[4];
        {
            const bf16x8 a0 = *(const bf16x8*)&us[l15 * 72 + l4 * 8];
            const bf16x8 a1 = *(const bf16x8*)&us[l15 * 72 + 32 + l4 * 8];
            #pragma unroll
            for (int t = 0; t < 4; ++t) {
                acc2[t] = __builtin_amdgcn_mfma_f32_16x16x32_bf16(bw2f[t][0], a0, zf, 0, 0, 0);
                acc2[t] = __builtin_amdgcn_mfma_f32_16x16x32_bf16(bw2f[t][1], a1, acc2[t], 0, 0, 0);
            }
        }
        LDS_FENCE();
        #pragma unroll
        for (int t = 0; t < 4; ++t) {
            const f32x4 b2v = cst_s[2][t * 4 + l4];
            bf16x4 mm;
            #pragma unroll
            for (int r = 0; r < 4; ++r)
                mm[r] = f2bf(silu_f(acc2[t][r] + b2v[r]));
            *(bf16x4*)&us[l15 * 72 + t * 16 + l4 * 4] = mm;
        }
        LDS_FENCE();

        // ---- layer3 MFMAs (issue before atomics so they overlap)
        f32x4 acc3[4];
        {
            const bf16x8 a0 = *(const bf16x8*)&us[l15 * 72 + l4 * 8];
            const bf16x8 a1 = *(const bf16x8*)&us[l15 * 72 + 32 + l4 * 8];
            #pragma unroll
            for (int t = 0; t < 4; ++t) {
                acc3[t] = __builtin_amdgcn_mfma_f32_16x16x32_bf16(bwc1f[t][0], a0, zf, 0, 0, 0);
                acc3[t] = __builtin_amdgcn_mfma_f32_16x16x32_bf16(bwc1f[t][1], a1, acc3[t], 0, 0, 0);
            }
        }

        // ---- tot_msg atomics, packed bf16x2, coalesced (1 line/row/instr)
        #pragma unroll
        for (int r = 0; r < 4; ++r) {
            const int er   = l4 * 4 + r;
            const int rowr = __shfl(cr, er);
            unsigned short* const mb = tot_msg + (size_t)rowr * 64;
            #pragma unroll
            for (int t = 0; t < 2; ++t) {
                const unsigned int pk = *(const unsigned int*)&us[er * 72 + t * 32 + l15 * 2];
                atomic_pk_add_bf16(mb + t * 32 + l15 * 2, pk);
            }
        }

        // ---- coord head
        float p = 0.f;
        #pragma unroll
        for (int t = 0; t < 4; ++t) {
            const f32x4 bcv = cst_s[3][t * 4 + l4];
            const f32x4 wcv = cst_s[4][t * 4 + l4];
            #pragma unroll
            for (int r = 0; r < 4; ++r)
                p += silu_f(acc3[t][r] + bcv[r]) * wcv[r];
        }
        p += __shfl_xor(p, 16);
        p += __shfl_xor(p, 32);
        const float coord = p + bc2v;

        const float comp = (l4 == 0) ? dx : (l4 == 1) ? dy : (l4 == 2) ? dz : 0.f;
        const float val  = (l4 == 3) ? 1.0f : comp * coord;
        atomicAdd(&totf4[(size_t)cr * 4 + l4], val);

        if (!hn) break;
        cr = nrow; g = gn;
        {
            const int g2 = gn + gstep;
            if (g2 < groups) { const int e = g2 * 64 + wv * 16 + l15; ibR = row[e]; ibC = col[e]; }
        }
    }
}

// ---------------------------------------------------------------- K3: nodes
__global__ __launch_bounds__(256, 2) void node_kernel(
    const float* __restrict__ x, const float* __restrict__ h,
    const unsigned short* __restrict__ wfrag,
    const float* __restrict__ bn1, const float* __restrict__ bn2,
    const unsigned short* __restrict__ tot_msg, const float* __restrict__ totf4,
    float* __restrict__ out)
{
    __shared__ __align__(16) short g_s[4][16 * 72];

    const int tid  = threadIdx.x;
    const int lane = tid & 63;
    const int wv   = __builtin_amdgcn_readfirstlane(tid >> 6);
    const int l15  = lane & 15;
    const int l4   = lane >> 4;

    bf16x8 awn1[4][4], awn2[4][2];
    f32x4 bn1r4[4], bn2r4[4];
    #pragma unroll
    for (int t = 0; t < 4; ++t) {
        #pragma unroll
        for (int s = 0; s < 4; ++s)
            awn1[t][s] = load_frag(wfrag, FR_WN1 + t * 4 + s, lane);
        #pragma unroll
        for (int s = 0; s < 2; ++s)
            awn2[t][s] = load_frag(wfrag, FR_WN2 + t * 2 + s, lane);
        bn1r4[t] = *(const f32x4*)&bn1[t * 16 + l4 * 4];
        bn2r4[t] = *(const f32x4*)&bn2[t * 16 + l4 * 4];
    }

    const f32x4 zf = {0.f, 0.f, 0.f, 0.f};
    const int n_groups = (N_NODES + 63) / 64;
    float* const out_h = out + (size_t)N_NODES * 3;

    for (int g = blockIdx.x; g < n_groups; g += gridDim.x) {
        const int n16  = g * 64 + wv * 16 + l15;
        const int nc   = (n16 < N_NODES) ? n16 : 0;
        const bool valid = (n16 < N_NODES);

        bf16x8 b[4];
        #pragma unroll
        for (int s = 0; s < 2; ++s) {
            const float* src = h + (size_t)nc * 64 + s * 32 + l4 * 8;
            const f32x4 f0 = *(const f32x4*)src;
            const f32x4 f1 = *(const f32x4*)(src + 4);
            bf16x8 bv;
            #pragma unroll
            for (int j = 0; j < 4; ++j) { bv[j] = f2bf(f0[j]); bv[4 + j] = f2bf(f1[j]); }
            b[s] = bv;
        }
        b[2] = *(const bf16x8*)(tot_msg + (size_t)nc * 64 + l4 * 8);
        b[3] = *(const bf16x8*)(tot_msg + (size_t)nc * 64 + 32 + l4 * 8);

        #pragma unroll
        for (int t = 0; t < 4; ++t) {
            f32x4 acc = __builtin_amdgcn_mfma_f32_16x16x32_bf16(awn1[t][0], b[0], zf, 0, 0, 0);
            acc = __builtin_amdgcn_mfma_f32_16x16x32_bf16(awn1[t][1], b[1], acc, 0, 0, 0);
            acc = __builtin_amdgcn_mfma_f32_16x16x32_bf16(awn1[t][2], b[2], acc, 0, 0, 0);
            acc = __builtin_amdgcn_mfma_f32_16x16x32_bf16(awn1[t][3], b[3], acc, 0, 0, 0);
            bf16x4 gg;
            #pragma unroll
            for (int r = 0; r < 4; ++r)
                gg[r] = f2bf(silu_f(acc[r] + bn1r4[t][r]));
            *(bf16x4*)&g_s[wv][l15 * 72 + t * 16 + l4 * 4] = gg;
        }
        LDS_FENCE();

        {
            const bf16x8 g0 = *(const bf16x8*)&g_s[wv][l15 * 72 + l4 * 8];
            const bf16x8 g1 = *(const bf16x8*)&g_s[wv][l15 * 72 + 32 + l4 * 8];
            #pragma unroll
            for (int t = 0; t < 4; ++t) {
                f32x4 acc = __builtin_amdgcn_mfma_f32_16x16x32_bf16(awn2[t][0], g0, zf, 0, 0, 0);
                acc = __builtin_amdgcn_mfma_f32_16x16x32_bf16(awn2[t][1], g1, acc, 0, 0, 0);
                if (valid) {
                    f32x4 o;
                    #pragma unroll
                    for (int r = 0; r < 4; ++r) o[r] = acc[r] + bn2r4[t][r];
                    *(f32x4*)&out_h[(size_t)n16 * 64 + t * 16 + l4 * 4] = o;
                }
            }
        }
        LDS_FENCE();

        if (lane < 48) {
            const int nn = lane / 3;
            const int ci = lane % 3;
            const int n  = g * 64 + wv * 16 + nn;
            if (n < N_NODES) {
                const float tot = totf4[n * 4 + ci];
                const float deg = totf4[n * 4 + 3];
                float v = tot / fmaxf(deg, 1.0f);
                v = fminf(fmaxf(v, -100.0f), 100.0f);
                out[n * 3 + ci] = x[n * 3 + ci] + v;
            }
        }
    }
}

// ---------------------------------------------------------------- launcher
extern "C" void kernel_launch(void* const* d_in, const int* in_sizes, int n_in,
                              void* d_out, int out_size, void* d_ws, size_t ws_size,
                              hipStream_t stream) {
    const float* x        = (const float*)d_in[0];
    const float* h        = (const float*)d_in[1];
    const float* edge_fea = (const float*)d_in[2];
    const float* w1e      = (const float*)d_in[3];
    const float* b1e      = (const float*)d_in[4];
    const float* w2e      = (const float*)d_in[5];
    const float* b2e      = (const float*)d_in[6];
    const float* wc1      = (const float*)d_in[7];
    const float* bc1      = (const float*)d_in[8];
    const float* wc2      = (const float*)d_in[9];
    const float* bc2      = (const float*)d_in[10];
    const float* wn1      = (const float*)d_in[11];
    const float* bn1      = (const float*)d_in[12];
    const float* wn2      = (const float*)d_in[13];
    const float* bn2      = (const float*)d_in[14];
    const int*   row      = (const int*)d_in[15];
    const int*   col      = (const int*)d_in[16];
    float* out = (float*)d_out;

    // ws layout: hA f32[N*64] | hB f32[N*64] | totf4 f32[N*4]
    //            | tot_msg bf16[N*64] | wfrag bf16[60*512]
    float* ws      = (float*)d_ws;
    float* hA      = ws;
    float* hB      = ws + (size_t)N_NODES * 64;
    float* totf4   = ws + (size_t)2 * N_NODES * 64;
    unsigned short* tot_msg = (unsigned short*)(ws + (size_t)2 * N_NODES * 64 + (size_t)N_NODES * 4);
    unsigned short* wfrag   = tot_msg + (size_t)N_NODES * 64;

    prep_weights<<<(FR_TOTAL * 64 + 255) / 256, 256, 0, stream>>>(w1e, w2e, wc1, wn1, wn2, wfrag);
    node_pre_kernel<<<782, 256, 0, stream>>>(h, wfrag, hA, hB, tot_msg, totf4);
    edge_kernel<<<2500, 256, 0, stream>>>(x, edge_fea, w1e, b1e, b2e, bc1, wc2, bc2,
                                          row, col, hA, hB, wfrag, tot_msg, totf4);
    node_kernel<<<782, 256, 0, stream>>>(x, h, wfrag, bn1, bn2, tot_msg, totf4, out);
}

// Round 9
// 280.355 us; speedup vs baseline: 3.1705x; 1.0552x over previous
//
#include <hip/hip_runtime.h>
#include <cstddef>

// EGNN layer. Round 9: node_pre eliminated — hA/hB folded into edge MFMAs.
//  - prep: weight frags + h->bf16 + zero tot_msg/totf4 (one kernel, ~27MB)
//  - edge layer1: acc1 = W1c^T@fea + Wa^T@h[row] + Wb^T@h[col] (chained MFMA);
//    h gathered directly as bf16 B-frags (2x16B per endpoint, 64B/row chunks)
//  - layer-1 weights (wa,wb,w1c) in registers; layer-2/3 (w2,wc1) in LDS
//  - ws shrinks 32.5MB -> 13.7MB; one fewer kernel launch
//  - aggregation unchanged: pk_add_bf16 tot_msg + f32 totf4 atomics
//
// MFMA fragment layouts (gfx950, 16x16x32 bf16, verified learn_hip m89/m91):
//   A: lane holds A[m=lane&15][k=(lane>>4)*8 + j], j=0..7
//   B: lane holds B[k=(lane>>4)*8 + j][n=lane&15]
//   C/D: lane reg r holds D[row=(lane>>4)*4+r][col=lane&15]

#define N_NODES 50000
#define M_EDGES 800000

typedef __attribute__((ext_vector_type(8))) short bf16x8;
typedef __attribute__((ext_vector_type(4))) short bf16x4;
typedef __attribute__((ext_vector_type(2))) short bf16x2;
typedef __attribute__((ext_vector_type(4))) float f32x4;

// fragment ids (each frag = 64 lanes x 8 shorts = 512 shorts)
#define FR_WA   0    // w1e rows 1..64    [t*2+s], 8 frags
#define FR_WB   8    // w1e rows 65..128  [t*2+s], 8 frags
#define FR_W1C  16   // w1e rows 129..144 (K-pad to 32) [t], 4 frags
#define FR_W2   20   // w2e [t*2+s], 8 frags   (contiguous with FR_WC1)
#define FR_WC1  28   // wc1 [t*2+s], 8 frags
#define FR_WN1  36   // wn1 (K=128) [t*4+s], 16 frags
#define FR_WN2  52   // wn2 [t*2+s], 8 frags
#define FR_TOTAL 60

__device__ __forceinline__ float silu_f(float v) {
    return v / (1.0f + __expf(-v));
}

__device__ __forceinline__ short f2bf(float f) {   // RNE float->bf16
    union { float f; unsigned u; } v; v.f = f;
    unsigned r = v.u + 0x7fffu + ((v.u >> 16) & 1u);
    return (short)(r >> 16);
}

__device__ __forceinline__ void atomic_pk_add_bf16(unsigned short* p, unsigned int packed) {
#if __has_builtin(__builtin_amdgcn_global_atomic_fadd_v2bf16)
    typedef bf16x2 __attribute__((address_space(1))) gbf16x2;
    union { unsigned int u; bf16x2 v; } c; c.u = packed;
    __builtin_amdgcn_global_atomic_fadd_v2bf16((gbf16x2*)(unsigned long long)p, c.v);
#else
    asm volatile("global_atomic_pk_add_bf16 %0, %1, off"
                 :: "v"((unsigned long long)p), "v"(packed) : "memory");
#endif
}

#define LDS_FENCE() __asm__ volatile("" ::: "memory")

__device__ __forceinline__ bf16x8 load_frag(const unsigned short* wfrag, int f, int lane) {
    return *(const bf16x8*)(wfrag + (size_t)f * 512 + lane * 8);
}

// ---------------------------------------------------------------- K0: prep
// wfrag conversion + h->bf16 + zero tot_msg/totf4, grid-strided.
#define PREP_W   (FR_TOTAL * 64)            // 3840
#define PREP_H   (N_NODES * 8)              // 400000  (bf16x8 items of h)
#define PREP_ZM  (N_NODES * 8)              // 400000  (uint4 items of tot_msg)
#define PREP_ZF  (N_NODES)                  // 50000   (f32x4 items of totf4)
#define PREP_TOTAL (PREP_W + PREP_H + PREP_ZM + PREP_ZF)

__global__ __launch_bounds__(256) void prep_kernel(
    const float* __restrict__ w1e, const float* __restrict__ w2e,
    const float* __restrict__ wc1, const float* __restrict__ wn1,
    const float* __restrict__ wn2, const float* __restrict__ h,
    unsigned short* __restrict__ wfrag, unsigned short* __restrict__ h_bf,
    unsigned short* __restrict__ tot_msg, float* __restrict__ totf4)
{
    for (int gid = blockIdx.x * 256 + threadIdx.x; gid < PREP_TOTAL;
         gid += gridDim.x * 256) {
        if (gid < PREP_W) {
            const int frag = gid >> 6, lane = gid & 63;
            const int l15 = lane & 15, l4 = lane >> 4;
            const float* src; int k0, t; bool pad16 = false;
            if (frag < FR_WB)        { const int f = frag - FR_WA;  t = f >> 1; src = w1e; k0 = 1 + (f & 1) * 32; }
            else if (frag < FR_W1C)  { const int f = frag - FR_WB;  t = f >> 1; src = w1e; k0 = 65 + (f & 1) * 32; }
            else if (frag < FR_W2)   { t = frag - FR_W1C; src = w1e; k0 = 129; pad16 = true; }
            else if (frag < FR_WC1)  { const int f = frag - FR_W2;  t = f >> 1; src = w2e; k0 = (f & 1) * 32; }
            else if (frag < FR_WN1)  { const int f = frag - FR_WC1; t = f >> 1; src = wc1; k0 = (f & 1) * 32; }
            else if (frag < FR_WN2)  { const int f = frag - FR_WN1; t = f >> 2; src = wn1; k0 = (f & 3) * 32; }
            else                     { const int f = frag - FR_WN2; t = f >> 1; src = wn2; k0 = (f & 1) * 32; }
            const int col = t * 16 + l15;
            bf16x8 v;
            #pragma unroll
            for (int j = 0; j < 8; ++j) {
                const int k = l4 * 8 + j;
                const float xv = (pad16 && k >= 16) ? 0.f : src[(size_t)(k0 + k) * 64 + col];
                v[j] = f2bf(xv);
            }
            *(bf16x8*)(wfrag + (size_t)frag * 512 + lane * 8) = v;
        } else if (gid < PREP_W + PREP_H) {
            const int j = gid - PREP_W;
            const float* src = h + (size_t)j * 8;
            const f32x4 f0 = *(const f32x4*)src;
            const f32x4 f1 = *(const f32x4*)(src + 4);
            bf16x8 v;
            #pragma unroll
            for (int k = 0; k < 4; ++k) { v[k] = f2bf(f0[k]); v[4 + k] = f2bf(f1[k]); }
            *(bf16x8*)(h_bf + (size_t)j * 8) = v;
        } else if (gid < PREP_W + PREP_H + PREP_ZM) {
            const int j = gid - PREP_W - PREP_H;
            ((uint4*)tot_msg)[j] = make_uint4(0u, 0u, 0u, 0u);
        } else {
            const int j = gid - PREP_W - PREP_H - PREP_ZM;
            const f32x4 zf = {0.f, 0.f, 0.f, 0.f};
            ((f32x4*)totf4)[j] = zf;
        }
    }
}

// ---------------------------------------------------------------- K2: edges
__global__ __launch_bounds__(256, 2) void edge_kernel(
    const float* __restrict__ x, const float* __restrict__ edge_fea,
    const float* __restrict__ w1e, const float* __restrict__ b1e,
    const float* __restrict__ b2e, const float* __restrict__ bc1,
    const float* __restrict__ wc2, const float* __restrict__ bc2,
    const int* __restrict__ row, const int* __restrict__ col,
    const unsigned short* __restrict__ h_bf,
    const unsigned short* __restrict__ wfrag,
    unsigned short* __restrict__ tot_msg, float* __restrict__ totf4)
{
    __shared__ __align__(16) short wlds[16 * 512];   // w2 (8) + wc1 (8) frags
    __shared__ __align__(16) short u_s[4][16 * 72];  // per-wave activation tile
    __shared__ f32x4 cst_s[5][16];                   // b1,w1r0,b2,bc1,wc2

    const int tid  = threadIdx.x;
    const int lane = tid & 63;
    const int wv   = __builtin_amdgcn_readfirstlane(tid >> 6);
    const int l15  = lane & 15;
    const int l4   = lane >> 4;

    {   // stage w2+wc1 frags (contiguous FR_W2..FR_WC1+8) into LDS: 16KB
        const uint4* src = (const uint4*)(wfrag + (size_t)FR_W2 * 512);
        uint4* dst = (uint4*)wlds;
        for (int i = tid; i < 1024; i += 256) dst[i] = src[i];
    }
    if (tid < 16)       cst_s[0][tid]      = *(const f32x4*)(b1e + tid * 4);
    else if (tid < 32)  cst_s[1][tid - 16] = *(const f32x4*)(w1e + (tid - 16) * 4);
    else if (tid < 48)  cst_s[2][tid - 32] = *(const f32x4*)(b2e + (tid - 32) * 4);
    else if (tid < 64)  cst_s[3][tid - 48] = *(const f32x4*)(bc1 + (tid - 48) * 4);
    else if (tid < 80)  cst_s[4][tid - 64] = *(const f32x4*)(wc2 + (tid - 64) * 4);

    // layer-1 weight frags in registers
    bf16x8 bw1cf[4], waf[4][2], wbf[4][2];
    #pragma unroll
    for (int t = 0; t < 4; ++t) {
        bw1cf[t] = load_frag(wfrag, FR_W1C + t, lane);
        #pragma unroll
        for (int s = 0; s < 2; ++s) {
            waf[t][s] = load_frag(wfrag, FR_WA + t * 2 + s, lane);
            wbf[t][s] = load_frag(wfrag, FR_WB + t * 2 + s, lane);
        }
    }
    const float bc2v = bc2[0];
    __syncthreads();

    short* const us = &u_s[wv][0];
    const f32x4 zf = {0.f, 0.f, 0.f, 0.f};

    // ---- pipelined group loop
    const int groups = M_EDGES / 64;     // 12500
    const int gstep  = gridDim.x;
    int g = blockIdx.x;

    int   cr;
    float xr0, xr1, xr2, xc0, xc1, xc2;
    bf16x8 bhr0, bhr1, bhc0, bhc1;       // h[row], h[col] B-frags (K=64)
    f32x4 cf0 = zf, cf1 = zf;            // fea halves (l4<2 only)

    auto issue_gathers = [&](int gg, int rI, int cI) {
        const float* xr = x + (size_t)rI * 3;
        const float* xc = x + (size_t)cI * 3;
        xr0 = xr[0]; xr1 = xr[1]; xr2 = xr[2];
        xc0 = xc[0]; xc1 = xc[1]; xc2 = xc[2];
        const unsigned short* hr = h_bf + (size_t)rI * 64;
        const unsigned short* hc = h_bf + (size_t)cI * 64;
        bhr0 = *(const bf16x8*)(hr + l4 * 8);
        bhr1 = *(const bf16x8*)(hr + 32 + l4 * 8);
        bhc0 = *(const bf16x8*)(hc + l4 * 8);
        bhc1 = *(const bf16x8*)(hc + 32 + l4 * 8);
        if (l4 < 2) {
            const float* fp = edge_fea + (size_t)(gg * 64 + wv * 16 + l15) * 16 + l4 * 8;
            cf0 = *(const f32x4*)fp;
            cf1 = *(const f32x4*)(fp + 4);
        }
    };

    {   // warm-up
        const int e = g * 64 + wv * 16 + l15;
        const int iaR = row[e], iaC = col[e];
        issue_gathers(g, iaR, iaC);
        cr = iaR;
    }
    int ibR = 0, ibC = 0;
    {
        const int gn = g + gstep;
        if (gn < groups) { const int e = gn * 64 + wv * 16 + l15; ibR = row[e]; ibC = col[e]; }
    }

    while (true) {
        const float dx = xr0 - xc0, dy = xr1 - xc1, dz = xr2 - xc2;
        const float sq = dx * dx + dy * dy + dz * dz;

        bf16x8 bfea;
        {
            bf16x8 tv;
            #pragma unroll
            for (int j = 0; j < 4; ++j) { tv[j] = f2bf(cf0[j]); tv[4 + j] = f2bf(cf1[j]); }
            const bf16x8 zv = {0, 0, 0, 0, 0, 0, 0, 0};
            bfea = (l4 < 2) ? tv : zv;
        }

        // ---- layer1: acc1 = W1c^T@fea + Wa^T@h_r + Wb^T@h_c (chained MFMA)
        f32x4 acc1[4];
        #pragma unroll
        for (int t = 0; t < 4; ++t) {
            acc1[t] = __builtin_amdgcn_mfma_f32_16x16x32_bf16(bw1cf[t], bfea, zf, 0, 0, 0);
            acc1[t] = __builtin_amdgcn_mfma_f32_16x16x32_bf16(waf[t][0], bhr0, acc1[t], 0, 0, 0);
            acc1[t] = __builtin_amdgcn_mfma_f32_16x16x32_bf16(waf[t][1], bhr1, acc1[t], 0, 0, 0);
            acc1[t] = __builtin_amdgcn_mfma_f32_16x16x32_bf16(wbf[t][0], bhc0, acc1[t], 0, 0, 0);
            acc1[t] = __builtin_amdgcn_mfma_f32_16x16x32_bf16(wbf[t][1], bhc1, acc1[t], 0, 0, 0);
        }
        #pragma unroll
        for (int t = 0; t < 4; ++t) {
            const f32x4 b1v = cst_s[0][t * 4 + l4];
            const f32x4 w0v = cst_s[1][t * 4 + l4];
            bf16x4 uu;
            #pragma unroll
            for (int r = 0; r < 4; ++r) {
                const float pre = acc1[t][r] + sq * w0v[r] + b1v[r];
                uu[r] = f2bf(silu_f(pre));
            }
            *(bf16x4*)&us[l15 * 72 + t * 16 + l4 * 4] = uu;
        }
        LDS_FENCE();

        // ---- prefetch next group's gathers (frag regs consumed above)
        const int gn = g + gstep;
        const bool hn = (gn < groups);
        int nrow = cr;
        if (hn) { issue_gathers(gn, ibR, ibC); nrow = ibR; }

        // ---- layer2: msg' = silu(W2^T @ u1' + b2)  (w2 frags from LDS)
        f32x4 acc2[4];
        {
            const bf16x8 a0 = *(const bf16x8*)&us[l15 * 72 + l4 * 8];
            const bf16x8 a1 = *(const bf16x8*)&us[l15 * 72 + 32 + l4 * 8];
            #pragma unroll
            for (int t = 0; t < 4; ++t) {
                const bf16x8 w0 = *(const bf16x8*)&wlds[(size_t)(t * 2 + 0) * 512 + lane * 8];
                const bf16x8 w1 = *(const bf16x8*)&wlds[(size_t)(t * 2 + 1) * 512 + lane * 8];
                acc2[t] = __builtin_amdgcn_mfma_f32_16x16x32_bf16(w0, a0, zf, 0, 0, 0);
                acc2[t] = __builtin_amdgcn_mfma_f32_16x16x32_bf16(w1, a1, acc2[t], 0, 0, 0);
            }
        }
        LDS_FENCE();
        #pragma unroll
        for (int t = 0; t < 4; ++t) {
            const f32x4 b2v = cst_s[2][t * 4 + l4];
            bf16x4 mm;
            #pragma unroll
            for (int r = 0; r < 4; ++r)
                mm[r] = f2bf(silu_f(acc2[t][r] + b2v[r]));
            *(bf16x4*)&us[l15 * 72 + t * 16 + l4 * 4] = mm;
        }
        LDS_FENCE();

        // ---- layer3 MFMAs (wc1 frags from LDS; issued before atomics)
        f32x4 acc3[4];
        {
            const bf16x8 a0 = *(const bf16x8*)&us[l15 * 72 + l4 * 8];
            const bf16x8 a1 = *(const bf16x8*)&us[l15 * 72 + 32 + l4 * 8];
            #pragma unroll
            for (int t = 0; t < 4; ++t) {
                const bf16x8 w0 = *(const bf16x8*)&wlds[(size_t)(8 + t * 2 + 0) * 512 + lane * 8];
                const bf16x8 w1 = *(const bf16x8*)&wlds[(size_t)(8 + t * 2 + 1) * 512 + lane * 8];
                acc3[t] = __builtin_amdgcn_mfma_f32_16x16x32_bf16(w0, a0, zf, 0, 0, 0);
                acc3[t] = __builtin_amdgcn_mfma_f32_16x16x32_bf16(w1, a1, acc3[t], 0, 0, 0);
            }
        }

        // ---- tot_msg atomics, packed bf16x2, coalesced (1 line/row/instr)
        #pragma unroll
        for (int r = 0; r < 4; ++r) {
            const int er   = l4 * 4 + r;
            const int rowr = __shfl(cr, er);
            unsigned short* const mb = tot_msg + (size_t)rowr * 64;
            #pragma unroll
            for (int t = 0; t < 2; ++t) {
                const unsigned int pk = *(const unsigned int*)&us[er * 72 + t * 32 + l15 * 2];
                atomic_pk_add_bf16(mb + t * 32 + l15 * 2, pk);
            }
        }

        // ---- coord head
        float p = 0.f;
        #pragma unroll
        for (int t = 0; t < 4; ++t) {
            const f32x4 bcv = cst_s[3][t * 4 + l4];
            const f32x4 wcv = cst_s[4][t * 4 + l4];
            #pragma unroll
            for (int r = 0; r < 4; ++r)
                p += silu_f(acc3[t][r] + bcv[r]) * wcv[r];
        }
        p += __shfl_xor(p, 16);
        p += __shfl_xor(p, 32);
        const float coord = p + bc2v;

        const float comp = (l4 == 0) ? dx : (l4 == 1) ? dy : (l4 == 2) ? dz : 0.f;
        const float val  = (l4 == 3) ? 1.0f : comp * coord;
        atomicAdd(&totf4[(size_t)cr * 4 + l4], val);

        if (!hn) break;
        cr = nrow; g = gn;
        {
            const int g2 = gn + gstep;
            if (g2 < groups) { const int e = g2 * 64 + wv * 16 + l15; ibR = row[e]; ibC = col[e]; }
        }
    }
}

// ---------------------------------------------------------------- K3: nodes
__global__ __launch_bounds__(256, 2) void node_kernel(
    const float* __restrict__ x, const unsigned short* __restrict__ h_bf,
    const unsigned short* __restrict__ wfrag,
    const float* __restrict__ bn1, const float* __restrict__ bn2,
    const unsigned short* __restrict__ tot_msg, const float* __restrict__ totf4,
    float* __restrict__ out)
{
    __shared__ __align__(16) short g_s[4][16 * 72];

    const int tid  = threadIdx.x;
    const int lane = tid & 63;
    const int wv   = __builtin_amdgcn_readfirstlane(tid >> 6);
    const int l15  = lane & 15;
    const int l4   = lane >> 4;

    bf16x8 awn1[4][4], awn2[4][2];
    f32x4 bn1r4[4], bn2r4[4];
    #pragma unroll
    for (int t = 0; t < 4; ++t) {
        #pragma unroll
        for (int s = 0; s < 4; ++s)
            awn1[t][s] = load_frag(wfrag, FR_WN1 + t * 4 + s, lane);
        #pragma unroll
        for (int s = 0; s < 2; ++s)
            awn2[t][s] = load_frag(wfrag, FR_WN2 + t * 2 + s, lane);
        bn1r4[t] = *(const f32x4*)&bn1[t * 16 + l4 * 4];
        bn2r4[t] = *(const f32x4*)&bn2[t * 16 + l4 * 4];
    }

    const f32x4 zf = {0.f, 0.f, 0.f, 0.f};
    const int n_groups = (N_NODES + 63) / 64;
    float* const out_h = out + (size_t)N_NODES * 3;

    for (int g = blockIdx.x; g < n_groups; g += gridDim.x) {
        const int n16  = g * 64 + wv * 16 + l15;
        const int nc   = (n16 < N_NODES) ? n16 : 0;
        const bool valid = (n16 < N_NODES);

        bf16x8 b[4];
        b[0] = *(const bf16x8*)(h_bf + (size_t)nc * 64 + l4 * 8);
        b[1] = *(const bf16x8*)(h_bf + (size_t)nc * 64 + 32 + l4 * 8);
        b[2] = *(const bf16x8*)(tot_msg + (size_t)nc * 64 + l4 * 8);
        b[3] = *(const bf16x8*)(tot_msg + (size_t)nc * 64 + 32 + l4 * 8);

        #pragma unroll
        for (int t = 0; t < 4; ++t) {
            f32x4 acc = __builtin_amdgcn_mfma_f32_16x16x32_bf16(awn1[t][0], b[0], zf, 0, 0, 0);
            acc = __builtin_amdgcn_mfma_f32_16x16x32_bf16(awn1[t][1], b[1], acc, 0, 0, 0);
            acc = __builtin_amdgcn_mfma_f32_16x16x32_bf16(awn1[t][2], b[2], acc, 0, 0, 0);
            acc = __builtin_amdgcn_mfma_f32_16x16x32_bf16(awn1[t][3], b[3], acc, 0, 0, 0);
            bf16x4 gg;
            #pragma unroll
            for (int r = 0; r < 4; ++r)
                gg[r] = f2bf(silu_f(acc[r] + bn1r4[t][r]));
            *(bf16x4*)&g_s[wv][l15 * 72 + t * 16 + l4 * 4] = gg;
        }
        LDS_FENCE();

        {
            const bf16x8 g0 = *(const bf16x8*)&g_s[wv][l15 * 72 + l4 * 8];
            const bf16x8 g1 = *(const bf16x8*)&g_s[wv][l15 * 72 + 32 + l4 * 8];
            #pragma unroll
            for (int t = 0; t < 4; ++t) {
                f32x4 acc = __builtin_amdgcn_mfma_f32_16x16x32_bf16(awn2[t][0], g0, zf, 0, 0, 0);
                acc = __builtin_amdgcn_mfma_f32_16x16x32_bf16(awn2[t][1], g1, acc, 0, 0, 0);
                if (valid) {
                    f32x4 o;
                    #pragma unroll
                    for (int r = 0; r < 4; ++r) o[r] = acc[r] + bn2r4[t][r];
                    *(f32x4*)&out_h[(size_t)n16 * 64 + t * 16 + l4 * 4] = o;
                }
            }
        }
        LDS_FENCE();

        if (lane < 48) {
            const int nn = lane / 3;
            const int ci = lane % 3;
            const int n  = g * 64 + wv * 16 + nn;
            if (n < N_NODES) {
                const float tot = totf4[n * 4 + ci];
                const float deg = totf4[n * 4 + 3];
                float v = tot / fmaxf(deg, 1.0f);
                v = fminf(fmaxf(v, -100.0f), 100.0f);
                out[n * 3 + ci] = x[n * 3 + ci] + v;
            }
        }
    }
}

// ---------------------------------------------------------------- launcher
extern "C" void kernel_launch(void* const* d_in, const int* in_sizes, int n_in,
                              void* d_out, int out_size, void* d_ws, size_t ws_size,
                              hipStream_t stream) {
    const float* x        = (const float*)d_in[0];
    const float* h        = (const float*)d_in[1];
    const float* edge_fea = (const float*)d_in[2];
    const float* w1e      = (const float*)d_in[3];
    const float* b1e      = (const float*)d_in[4];
    const float* w2e      = (const float*)d_in[5];
    const float* b2e      = (const float*)d_in[6];
    const float* wc1      = (const float*)d_in[7];
    const float* bc1      = (const float*)d_in[8];
    const float* wc2      = (const float*)d_in[9];
    const float* bc2      = (const float*)d_in[10];
    const float* wn1      = (const float*)d_in[11];
    const float* bn1      = (const float*)d_in[12];
    const float* wn2      = (const float*)d_in[13];
    const float* bn2      = (const float*)d_in[14];
    const int*   row      = (const int*)d_in[15];
    const int*   col      = (const int*)d_in[16];
    float* out = (float*)d_out;

    // ws layout: totf4 f32[N*4] | tot_msg bf16[N*64] | h_bf bf16[N*64]
    //            | wfrag bf16[60*512]   (~13.7 MB total)
    float* totf4 = (float*)d_ws;
    unsigned short* tot_msg = (unsigned short*)(totf4 + (size_t)N_NODES * 4);
    unsigned short* h_bf    = tot_msg + (size_t)N_NODES * 64;
    unsigned short* wfrag   = h_bf + (size_t)N_NODES * 64;

    prep_kernel<<<1024, 256, 0, stream>>>(w1e, w2e, wc1, wn1, wn2, h,
                                          wfrag, h_bf, tot_msg, totf4);
    edge_kernel<<<2500, 256, 0, stream>>>(x, edge_fea, w1e, b1e, b2e, bc1, wc2, bc2,
                                          row, col, h_bf, wfrag, tot_msg, totf4);
    node_kernel<<<782, 256, 0, stream>>>(x, h_bf, wfrag, bn1, bn2, tot_msg, totf4, out);
}